// Round 6
// baseline (466.081 us; speedup 1.0000x reference)
//
#include <hip/hip_runtime.h>
#include <math.h>

#define NB 16
#define NPG 1024
#define DIN 16
#define ED 8
#define NHEADS 5
#define OUT1 6
#define HID 30
#define C1 32
#define C2 4
#define NN (NB*NPG)      // 16384 nodes
#define EE (NN*32)       // 524288 edges
#define EPG 32768        // edges per graph (graph-contiguous in edge_index)

__device__ __forceinline__ float lrelu(float v){ return v >= 0.f ? v : 0.2f*v; }

// ---------- Stage 1 prep: h1 = x@W1 ; per-node attention scalars ----------
__global__ void k_node_proj1(const float* __restrict__ x, const float* __restrict__ W1,
                             const float* __restrict__ as1, const float* __restrict__ ad1,
                             float* __restrict__ h1, float* __restrict__ hs1, float* __restrict__ hd1){
    __shared__ float Ws[DIN*HID];
    __shared__ float as_s[HID], ad_s[HID];
    for (int i = threadIdx.x; i < DIN*HID; i += blockDim.x) Ws[i] = W1[i];
    if (threadIdx.x < HID){ as_s[threadIdx.x] = as1[threadIdx.x]; ad_s[threadIdx.x] = ad1[threadIdx.x]; }
    __syncthreads();
    int n = blockIdx.x*blockDim.x + threadIdx.x;
    if (n >= NN) return;
    float xv[DIN];
    #pragma unroll
    for (int i = 0; i < DIN; i++) xv[i] = x[n*DIN + i];
    float hv[HID];
    #pragma unroll
    for (int j = 0; j < HID; j++){
        float a = 0.f;
        #pragma unroll
        for (int i = 0; i < DIN; i++) a += xv[i]*Ws[i*HID + j];
        hv[j] = a; h1[(size_t)n*HID + j] = a;
    }
    #pragma unroll
    for (int h = 0; h < NHEADS; h++){
        float s = 0.f, d = 0.f;
        #pragma unroll
        for (int c = 0; c < OUT1; c++){ s += hv[h*OUT1+c]*as_s[h*OUT1+c]; d += hv[h*OUT1+c]*ad_s[h*OUT1+c]; }
        hs1[n*NHEADS + h] = s; hd1[n*NHEADS + h] = d;
    }
}

// ---------- graph-local CSR build (one workgroup per graph per pass) ----------
// blocks 0..15  : pass A — dst-CSR (srcs, rowptr) + fused edge projections
// blocks 16..31 : pass B — src-CSR (nbrS, rowptrS)
// All histogram/scan/scatter in LDS; every global write coalesced or
// graph-window-local (single XCD) -> no cross-XCD write amplification.
__global__ __launch_bounds__(1024) void k_csr(const int* __restrict__ src,
        const int* __restrict__ dst, const float* __restrict__ ea,
        const float* __restrict__ We1, const float* __restrict__ Wep1,
        int* __restrict__ rowptr, int* __restrict__ rowptrS,
        int* __restrict__ srcs, int* __restrict__ nbrS,
        float* __restrict__ ew1s, float* __restrict__ ewp1s){
    __shared__ int ebuf[EPG];          // 128 KB slot->payload buffer
    __shared__ int hist[NPG];
    __shared__ int sums[NPG];
    __shared__ float Wsh[ED*NHEADS + ED];
    int t = threadIdx.x;
    bool passA = (blockIdx.x < NB);
    int b = passA ? blockIdx.x : (blockIdx.x - NB);
    size_t ebase = (size_t)b*EPG;
    int nbase = b*NPG;
    const int* key = passA ? dst : src;   // sort key
    const int* val = passA ? src : dst;   // payload stored at the slot
    hist[t] = 0;
    if (passA && t < ED*NHEADS + ED)
        Wsh[t] = (t < ED*NHEADS) ? We1[t] : Wep1[t - ED*NHEADS];
    __syncthreads();
    // 1. histogram (keys are graph-local)
    int kloc[32];
    #pragma unroll
    for (int i = 0; i < 32; i++){
        int k = key[ebase + i*1024 + t] & (NPG-1);
        kloc[i] = k;
        atomicAdd(&hist[k], 1);
    }
    __syncthreads();
    // 2. exclusive scan over 1024 counters
    sums[t] = hist[t];
    __syncthreads();
    for (int off = 1; off < 1024; off <<= 1){
        int v = (t >= off) ? sums[t-off] : 0;
        __syncthreads();
        sums[t] += v;
        __syncthreads();
    }
    int excl = (t == 0) ? 0 : sums[t-1];
    int* rp = passA ? rowptr : rowptrS;
    rp[nbase + t] = (int)ebase + excl;
    if (b == NB-1 && t == 1023) rp[NN] = EE;
    hist[t] = excl;                    // reuse as fill cursor
    __syncthreads();
    // 3. scatter payloads into LDS slots
    int p[32];
    #pragma unroll
    for (int i = 0; i < 32; i++){
        int pp = atomicAdd(&hist[kloc[i]], 1);
        p[i] = pp;
        ebuf[pp] = val[ebase + i*1024 + t];
    }
    __syncthreads();
    // 4. coalesced writeout of the sorted payload
    int* outarr = passA ? srcs : nbrS;
    #pragma unroll
    for (int i = 0; i < 32; i++)
        outarr[ebase + i*1024 + t] = ebuf[i*1024 + t];
    // 5. pass A only: edge-attr projections written at CSR slots
    //    (scatter confined to this graph's 768 KB window on this XCD's L2)
    if (passA){
        for (int i = 0; i < 32; i++){
            size_t e = ebase + (size_t)i*1024 + t;
            float a[ED];
            #pragma unroll
            for (int j = 0; j < ED; j++) a[j] = ea[e*ED + j];
            size_t pp = ebase + (size_t)p[i];
            #pragma unroll
            for (int h = 0; h < NHEADS; h++){
                float sv = 0.f;
                #pragma unroll
                for (int j = 0; j < ED; j++) sv += a[j]*Wsh[j*NHEADS + h];
                ew1s[pp*NHEADS + h] = sv;
            }
            float sv = 0.f;
            #pragma unroll
            for (int j = 0; j < ED; j++) sv += a[j]*Wsh[ED*NHEADS + j];
            ewp1s[pp] = sv;
        }
    }
}

// ---------- dedup via per-thread LDS bitmap (neighbors are block-local 0..1023) ----------
__global__ void k_dedup(const int* __restrict__ rowptrS, const int* __restrict__ nbrS,
                        int* __restrict__ unbr, int* __restrict__ ucnt,
                        float* __restrict__ scal){
    __shared__ unsigned int bm[256*33];   // 33-word stride: bank = (t + w) & 31
    int t = threadIdx.x;
    unsigned int* mybm = &bm[t*33];
    #pragma unroll
    for (int i = 0; i < 32; i++) mybm[i] = 0u;
    int n = blockIdx.x*blockDim.x + t;
    int cnt = 0;
    if (n < NN){
        int k0 = rowptrS[n], k1 = rowptrS[n+1];
        for (int k = k0; k < k1; k++){
            int m = nbrS[k];
            int loc = m & (NPG-1);
            unsigned int w = (unsigned int)(loc >> 5);
            unsigned int bit = 1u << (loc & 31);
            unsigned int old = mybm[w];
            if (!(old & bit)){
                mybm[w] = old | bit;
                unbr[k0 + cnt] = m;
                cnt++;
            }
        }
        ucnt[n] = cnt;
    }
    __shared__ int red[256];
    red[t] = cnt; __syncthreads();
    for (int s = 128; s > 0; s >>= 1){ if (t < s) red[t] += red[t+s]; __syncthreads(); }
    if (t == 0) atomicAdd(&scal[0], (float)red[0]);
}

// ---------- conv1 aggregation: online softmax, one thread per (node, head) ----------
__global__ void k_conv1_agg(const int* __restrict__ srcs, const int* __restrict__ rowptr,
                            const float* __restrict__ h1,
                            const float* __restrict__ hs1, const float* __restrict__ hd1,
                            const float* __restrict__ ew1s, float* __restrict__ x1){
    int tid = blockIdx.x*blockDim.x + threadIdx.x;
    if (tid >= NN*NHEADS) return;
    int h = tid % NHEADS;
    int n = tid / NHEADS;
    int k0 = rowptr[n], k1 = rowptr[n+1];
    float hdv = hd1[n*NHEADS + h];
    float m = -INFINITY, den = 0.f;
    float acc[OUT1];
    #pragma unroll
    for (int c = 0; c < OUT1; c++) acc[c] = 0.f;
    for (int k = k0; k < k1; k++){
        int s = srcs[k];
        float l = lrelu(hs1[s*NHEADS + h] + hdv + ew1s[(size_t)k*NHEADS + h]);
        float mn = fmaxf(m, l);
        float f  = expf(m - mn);     // first iter: exp(-inf)=0
        float ex = expf(l - mn);
        m = mn;
        den = den*f + ex;
        const float* hr = h1 + (size_t)s*HID + h*OUT1;
        #pragma unroll
        for (int c = 0; c < OUT1; c++) acc[c] = acc[c]*f + ex*hr[c];
    }
    float inv = 1.f / (den + 1e-16f);
    #pragma unroll
    for (int c = 0; c < OUT1; c++) x1[(size_t)n*HID + h*OUT1 + c] = acc[c]*inv;
}

// ---------- pool-conv1 prep: hp1 = x1@Wp1 (30x32); scalars ----------
__global__ void k_node_proj_p1(const float* __restrict__ x1, const float* __restrict__ Wp1,
                               const float* __restrict__ asp, const float* __restrict__ adp,
                               float* __restrict__ hp1, float* __restrict__ hsp, float* __restrict__ hdp){
    __shared__ float Ws[HID*C1];
    __shared__ float as_s[C1], ad_s[C1];
    for (int i = threadIdx.x; i < HID*C1; i += blockDim.x) Ws[i] = Wp1[i];
    if (threadIdx.x < C1){ as_s[threadIdx.x] = asp[threadIdx.x]; ad_s[threadIdx.x] = adp[threadIdx.x]; }
    __syncthreads();
    int n = blockIdx.x*blockDim.x + threadIdx.x;
    if (n >= NN) return;
    float xv[HID];
    #pragma unroll
    for (int d = 0; d < HID; d++) xv[d] = x1[(size_t)n*HID + d];
    float s = 0.f, dd = 0.f;
    for (int c = 0; c < C1; c++){
        float a = 0.f;
        #pragma unroll
        for (int d = 0; d < HID; d++) a += xv[d]*Ws[d*C1 + c];
        hp1[(size_t)n*C1 + c] = a;
        s += a*as_s[c]; dd += a*ad_s[c];
    }
    hsp[n] = s; hdp[n] = dd;
}

// ---------- pool-conv1 aggregation: online softmax, thread per (node, 8-ch quarter) ----------
__global__ void k_pool1_agg(const int* __restrict__ srcs, const int* __restrict__ rowptr,
                            const float* __restrict__ hp1,
                            const float* __restrict__ hsp, const float* __restrict__ hdp,
                            const float* __restrict__ ewp1s, float* __restrict__ s1){
    int tid = blockIdx.x*blockDim.x + threadIdx.x;
    if (tid >= NN*4) return;
    int q = tid & 3;
    int n = tid >> 2;
    int k0 = rowptr[n], k1 = rowptr[n+1];
    float hdv = hdp[n];
    float m = -INFINITY, den = 0.f;
    float acc[8];
    #pragma unroll
    for (int c = 0; c < 8; c++) acc[c] = 0.f;
    for (int k = k0; k < k1; k++){
        int s = srcs[k];
        float l = lrelu(hsp[s] + hdv + ewp1s[k]);
        float mn = fmaxf(m, l);
        float f  = expf(m - mn);
        float ex = expf(l - mn);
        m = mn;
        den = den*f + ex;
        const float* hr = hp1 + (size_t)s*C1 + q*8;
        #pragma unroll
        for (int c = 0; c < 8; c++) acc[c] = acc[c]*f + ex*hr[c];
    }
    float inv = 1.f / (den + 1e-16f);
    #pragma unroll
    for (int c = 0; c < 8; c++) s1[(size_t)n*C1 + q*8 + c] = acc[c]*inv;
}

// ---------- cluster softmax (over 32) ----------
__global__ void k_soft32(const float* __restrict__ s1, float* __restrict__ ssoft){
    int n = blockIdx.x*blockDim.x + threadIdx.x;
    if (n >= NN) return;
    float v[C1];
    float m = -INFINITY;
    #pragma unroll
    for (int c = 0; c < C1; c++){ v[c] = s1[(size_t)n*C1 + c]; m = fmaxf(m, v[c]); }
    float sum = 0.f;
    #pragma unroll
    for (int c = 0; c < C1; c++){ v[c] = expf(v[c] - m); sum += v[c]; }
    float inv = 1.f/sum;
    #pragma unroll
    for (int c = 0; c < C1; c++) ssoft[(size_t)n*C1 + c] = v[c]*inv;
}

// ---------- T[n,:] = sum over unique out-neighbors m of S[m,:] ----------
__global__ void k_T(const int* __restrict__ rowptrS, const int* __restrict__ unbr,
                    const int* __restrict__ ucnt, const float* __restrict__ ssoft,
                    float* __restrict__ T){
    int tid = blockIdx.x*blockDim.x + threadIdx.x;
    if (tid >= NN*4) return;
    int q = tid & 3;
    int n = tid >> 2;
    int k0 = rowptrS[n];
    int cnt = ucnt[n];
    float acc[8];
    #pragma unroll
    for (int c = 0; c < 8; c++) acc[c] = 0.f;
    for (int i = 0; i < cnt; i++){
        int m = unbr[k0 + i];
        const float* sr = ssoft + (size_t)m*C1 + q*8;
        #pragma unroll
        for (int c = 0; c < 8; c++) acc[c] += sr[c];
    }
    #pragma unroll
    for (int c = 0; c < 8; c++) T[(size_t)n*C1 + q*8 + c] = acc[c];
}

// ---------- fused partials over 64-node chunks:
//   adj2 += S_chunk^T T_chunk ; G += S_chunk^T S_chunk ; x2 += S_chunk^T X_chunk
__global__ void k_partials(const float* __restrict__ ssoft, const float* __restrict__ T,
                           const float* __restrict__ x1,
                           float* __restrict__ adj2, float* __restrict__ Gm,
                           float* __restrict__ x2){
    int b  = blockIdx.y;
    int n0 = blockIdx.x * 64;
    int t  = threadIdx.x;   // 256
    __shared__ float ssh[64*C1];
    __shared__ float tsh[64*C1];
    __shared__ float xsh[64*HID];
    {
        size_t sbase = ((size_t)b*NPG + n0)*C1;
        #pragma unroll
        for (int i = 0; i < 8; i++){
            int lin = t + i*256;
            ssh[lin] = ssoft[sbase + lin];
            tsh[lin] = T[sbase + lin];
        }
        size_t xbase = ((size_t)b*NPG + n0)*HID;
        for (int lin = t; lin < 64*HID; lin += 256) xsh[lin] = x1[xbase + lin];
    }
    __syncthreads();
    float accA[4] = {0,0,0,0}, accG[4] = {0,0,0,0}, accX[4] = {0,0,0,0};
    int cA[4], kA[4], cX[4], dX[4];
    #pragma unroll
    for (int q = 0; q < 4; q++){
        int p = t + q*256;
        cA[q] = p >> 5; kA[q] = p & 31;
        cX[q] = p / HID; dX[q] = p - cX[q]*HID;   // valid only when p < 960
    }
    for (int r = 0; r < 64; r++){
        const float* sr = ssh + r*C1;
        const float* tr = tsh + r*C1;
        const float* xr = xsh + r*HID;
        #pragma unroll
        for (int q = 0; q < 4; q++){
            float sc = sr[cA[q]];
            accA[q] += sc*tr[kA[q]];
            accG[q] += sc*sr[kA[q]];
        }
        #pragma unroll
        for (int q = 0; q < 4; q++){
            int p = t + q*256;
            if (p < C1*HID) accX[q] += sr[cX[q]]*xr[dX[q]];
        }
    }
    #pragma unroll
    for (int q = 0; q < 4; q++){
        int p = t + q*256;
        atomicAdd(&adj2[(size_t)b*1024 + p], accA[q]);
        atomicAdd(&Gm[(size_t)b*1024 + p], accG[q]);
        if (p < C1*HID) atomicAdd(&x2[((size_t)b*C1 + cX[q])*HID + dX[q]], accX[q]);
    }
}

// ---------- finalize reg1 ingredients: trace(adj2), ||G||_F^2 ----------
__global__ void k_finalize(const float* __restrict__ adj2, const float* __restrict__ Gm,
                           float* __restrict__ scal){
    int b = blockIdx.x;
    int t = threadIdx.x;   // 256
    float ltr = 0.f, lfr = 0.f;
    for (int p = t; p < 1024; p += 256){
        float g = Gm[(size_t)b*1024 + p];
        lfr += g*g;
        if ((p >> 5) == (p & 31)) ltr += adj2[(size_t)b*1024 + p];
    }
    __shared__ float red[256];
    red[t] = ltr; __syncthreads();
    for (int s = 128; s > 0; s >>= 1){ if (t < s) red[t] += red[t+s]; __syncthreads(); }
    if (t == 0) atomicAdd(&scal[1], red[0]);
    __syncthreads();
    red[t] = lfr; __syncthreads();
    for (int s = 128; s > 0; s >>= 1){ if (t < s) red[t] += red[t+s]; __syncthreads(); }
    if (t == 0) atomicAdd(&scal[2], red[0]);
}

// ---------- pool-conv2 prep ----------
__global__ void k_node_proj2(const float* __restrict__ x2, const float* __restrict__ Wp2,
                             const float* __restrict__ asp, const float* __restrict__ adp,
                             float* __restrict__ h2, float* __restrict__ hs2, float* __restrict__ hd2){
    __shared__ float Ws[HID*C2];
    __shared__ float as_s[C2], ad_s[C2];
    for (int i = threadIdx.x; i < HID*C2; i += blockDim.x) Ws[i] = Wp2[i];
    if (threadIdx.x < C2){ as_s[threadIdx.x] = asp[threadIdx.x]; ad_s[threadIdx.x] = adp[threadIdx.x]; }
    __syncthreads();
    int n = blockIdx.x*blockDim.x + threadIdx.x;
    if (n >= NB*C1) return;
    float xv[HID];
    #pragma unroll
    for (int d = 0; d < HID; d++) xv[d] = x2[(size_t)n*HID + d];
    float s = 0.f, dd = 0.f;
    #pragma unroll
    for (int c = 0; c < C2; c++){
        float a = 0.f;
        #pragma unroll
        for (int d = 0; d < HID; d++) a += xv[d]*Ws[d*C2 + c];
        h2[n*C2 + c] = a;
        s += a*as_s[c]; dd += a*ad_s[c];
    }
    hs2[n] = s; hd2[n] = dd;
}

// ---------- pool-conv2 aggregation (dense 32-in per dst, attr = adj2) ----------
__global__ void k_pool2_agg(const float* __restrict__ h2, const float* __restrict__ hs2,
                            const float* __restrict__ hd2, const float* __restrict__ adj2,
                            const float* __restrict__ Wep2, float* __restrict__ s2){
    int n = blockIdx.x*blockDim.x + threadIdx.x;   // dst node, 0..511
    if (n >= NB*C1) return;
    int b = n >> 5, j = n & 31;
    float hdv = hd2[n];
    float wep = Wep2[0];
    float m = -INFINITY;
    for (int i = 0; i < C1; i++){
        float l = lrelu(hs2[b*C1 + i] + hdv + adj2[(size_t)b*1024 + i*32 + j]*wep);
        m = fmaxf(m, l);
    }
    float den = 0.f;
    float acc[C2] = {0,0,0,0};
    for (int i = 0; i < C1; i++){
        float l = lrelu(hs2[b*C1 + i] + hdv + adj2[(size_t)b*1024 + i*32 + j]*wep);
        float ex = expf(l - m);
        den += ex;
        #pragma unroll
        for (int c = 0; c < C2; c++) acc[c] += ex * h2[(b*C1 + i)*C2 + c];
    }
    float inv = 1.f/(den + 1e-16f);
    #pragma unroll
    for (int c = 0; c < C2; c++) s2[n*C2 + c] = acc[c]*inv;
}

// ---------- diffpool2: softmax(s2), x3 = S^T x2, reg2 ----------
__global__ void k_pool2(const float* __restrict__ s2, const float* __restrict__ x2,
                        const float* __restrict__ adj2, float* __restrict__ x3,
                        float* __restrict__ scal){
    int b = blockIdx.x;
    int t = threadIdx.x;  // 256
    __shared__ float ss[C1*C2];
    __shared__ float xs[C1*HID];
    if (t < C1){
        float v[C2]; float m = -INFINITY;
        #pragma unroll
        for (int c = 0; c < C2; c++){ v[c] = s2[(b*C1 + t)*C2 + c]; m = fmaxf(m, v[c]); }
        float sum = 0.f;
        #pragma unroll
        for (int c = 0; c < C2; c++){ v[c] = expf(v[c] - m); sum += v[c]; }
        float inv = 1.f/sum;
        #pragma unroll
        for (int c = 0; c < C2; c++) ss[t*C2 + c] = v[c]*inv;
    }
    for (int lin = t; lin < C1*HID; lin += 256) xs[lin] = x2[(size_t)b*C1*HID + lin];
    __syncthreads();
    if (t < C2*HID){
        int c = t / HID, d = t % HID;
        float a = 0.f;
        #pragma unroll
        for (int n = 0; n < C1; n++) a += ss[n*C2 + c]*xs[n*HID + d];
        x3[(size_t)b*C2*HID + t] = a;
    }
    float loc = 0.f;
    for (int p = t; p < 1024; p += 256){
        int n = p >> 5, mm = p & 31;
        float dot = 0.f;
        #pragma unroll
        for (int c = 0; c < C2; c++) dot += ss[n*C2 + c]*ss[mm*C2 + c];
        float df = adj2[(size_t)b*1024 + p] - dot;
        loc += df*df;
    }
    __shared__ float red[256];
    red[t] = loc; __syncthreads();
    for (int s = 128; s > 0; s >>= 1){ if (t < s) red[t] += red[t+s]; __syncthreads(); }
    if (t == 0) atomicAdd(&scal[3], red[0]);
}

// ---------- final MLP + reg assembly ----------
__global__ void k_mlp(const float* __restrict__ x3, const float* __restrict__ Wf1,
                      const float* __restrict__ bf1, const float* __restrict__ Wf2,
                      const float* __restrict__ bf2, const float* __restrict__ scal,
                      float* __restrict__ out){
    __shared__ float zsh[NB*32];
    int t = threadIdx.x;   // 512
    if (t < NB*32){
        int b = t >> 5, j = t & 31;
        float a = bf1[j];
        const float* xr = x3 + (size_t)b*C2*HID;
        #pragma unroll 4
        for (int k = 0; k < C2*HID; k++) a += xr[k]*Wf1[k*32 + j];
        zsh[t] = fmaxf(a, 0.f);
    }
    __syncthreads();
    if (t < NB*2){
        int b = t >> 1, o = t & 1;
        float a = bf2[o];
        #pragma unroll
        for (int j = 0; j < 32; j++) a += zsh[b*32 + j]*Wf2[j*2 + o];
        out[t] = a;
    }
    if (t == 0){
        float adjsum = scal[0], tr = scal[1], fr = scal[2], r2 = scal[3];
        float reg1 = (adjsum - 2.f*tr + fr) * (1.f/16777216.f);
        float reg2 = r2 * (1.f/16384.f);
        out[32] = 10.f*reg1 + 0.1f*reg2;
    }
}

extern "C" void kernel_launch(void* const* d_in, const int* in_sizes, int n_in,
                              void* d_out, int out_size, void* d_ws, size_t ws_size,
                              hipStream_t stream) {
    const float* x    = (const float*)d_in[0];
    const int*   ei   = (const int*)d_in[1];
    const float* ea   = (const float*)d_in[2];
    // d_in[3] = y (unused); d_in[4] = adj (algebraically eliminated — never read)
    const float* W1   = (const float*)d_in[5];
    const float* as1  = (const float*)d_in[6];
    const float* ad1  = (const float*)d_in[7];
    const float* We1  = (const float*)d_in[8];
    const float* Wp1  = (const float*)d_in[9];
    const float* asp1 = (const float*)d_in[10];
    const float* adp1 = (const float*)d_in[11];
    const float* Wep1 = (const float*)d_in[12];
    const float* Wp2  = (const float*)d_in[13];
    const float* asp2 = (const float*)d_in[14];
    const float* adp2 = (const float*)d_in[15];
    const float* Wep2 = (const float*)d_in[16];
    const float* Wf1  = (const float*)d_in[17];
    const float* bf1  = (const float*)d_in[18];
    const float* Wf2  = (const float*)d_in[19];
    const float* bf2  = (const float*)d_in[20];
    float* out = (float*)d_out;

    const int* srcA = ei;
    const int* dstA = ei + EE;

    char* wp = (char*)d_ws;
    auto carve = [&](size_t bytes)->char*{
        char* p = wp;
        wp += (bytes + 255) & ~(size_t)255;
        return p;
    };
    float* h1    = (float*)carve((size_t)NN*HID*4);
    float* hs1   = (float*)carve((size_t)NN*NHEADS*4);
    float* hd1   = (float*)carve((size_t)NN*NHEADS*4);
    float* ew1s  = (float*)carve((size_t)EE*NHEADS*4);
    float* ewp1s = (float*)carve((size_t)EE*4);
    float* x1    = (float*)carve((size_t)NN*HID*4);
    float* hp1   = (float*)carve((size_t)NN*C1*4);
    float* hsp   = (float*)carve((size_t)NN*4);
    float* hdp   = (float*)carve((size_t)NN*4);
    float* s1    = (float*)carve((size_t)NN*C1*4);
    float* ssoft = (float*)carve((size_t)NN*C1*4);
    float* T     = (float*)carve((size_t)NN*C1*4);
    // --- zero-init region (contiguous): x2, adj2, Gm ---
    float* x2    = (float*)carve((size_t)NB*C1*HID*4);   // 61440 B (256-aligned)
    float* adj2  = (float*)carve((size_t)NB*C1*C1*4);    // 65536 B
    float* Gm    = (float*)carve((size_t)NB*C1*C1*4);    // 65536 B
    // ---------------------------------------------------
    float* h2    = (float*)carve((size_t)NB*C1*C2*4);
    float* hs2   = (float*)carve((size_t)NB*C1*4);
    float* hd2   = (float*)carve((size_t)NB*C1*4);
    float* s2    = (float*)carve((size_t)NB*C1*C2*4);
    float* x3    = (float*)carve((size_t)NB*C2*HID*4);
    float* scal  = (float*)carve(16*4);
    int* rowptr  = (int*)carve((size_t)(NN+1)*4);
    int* rowptrS = (int*)carve((size_t)(NN+1)*4);
    int* srcs    = (int*)carve((size_t)EE*4);
    int* nbrS    = (int*)carve((size_t)EE*4);
    int* unbr    = (int*)carve((size_t)EE*4);
    int* ucnt    = (int*)carve((size_t)NN*4);

    hipMemsetAsync(scal, 0, 16*4, stream);
    hipMemsetAsync(x2, 0, (size_t)(NB*C1*HID + 2*NB*C1*C1)*4, stream);  // x2+adj2+Gm

    const int TB = 256;
    dim3 gN((NN + TB - 1)/TB);

    // node projection (independent of graph structure)
    k_node_proj1<<<gN, TB, 0, stream>>>(x, W1, as1, ad1, h1, hs1, hd1);

    // graph-local CSR build + fused edge projections (replaces hist/scan/fill/scatter/edge_proj)
    k_csr<<<dim3(2*NB), 1024, 0, stream>>>(srcA, dstA, ea, We1, Wep1,
                                           rowptr, rowptrS, srcs, nbrS, ew1s, ewp1s);

    // dedup unique out-neighbors via LDS bitmap + sum(A)
    k_dedup<<<dim3(NN/TB), TB, 0, stream>>>(rowptrS, nbrS, unbr, ucnt, scal);

    // conv1: thread per (node, head), single-pass online softmax
    k_conv1_agg<<<dim3((NN*NHEADS + TB - 1)/TB), TB, 0, stream>>>(srcs, rowptr, h1, hs1, hd1, ew1s, x1);

    // pool-conv1
    k_node_proj_p1<<<gN, TB, 0, stream>>>(x1, Wp1, asp1, adp1, hp1, hsp, hdp);
    k_pool1_agg<<<dim3((NN*4 + TB - 1)/TB), TB, 0, stream>>>(srcs, rowptr, hp1, hsp, hdp, ewp1s, s1);

    // diffpool1
    k_soft32<<<gN, TB, 0, stream>>>(s1, ssoft);
    k_T<<<dim3((NN*4 + TB - 1)/TB), TB, 0, stream>>>(rowptrS, unbr, ucnt, ssoft, T);
    k_partials<<<dim3(16, NB), TB, 0, stream>>>(ssoft, T, x1, adj2, Gm, x2);
    k_finalize<<<dim3(NB), TB, 0, stream>>>(adj2, Gm, scal);

    // pool-conv2 on dense pooled graph
    k_node_proj2<<<dim3(2), TB, 0, stream>>>(x2, Wp2, asp2, adp2, h2, hs2, hd2);
    k_pool2_agg<<<dim3(2), TB, 0, stream>>>(h2, hs2, hd2, adj2, Wep2, s2);

    // diffpool2 + reg2
    k_pool2<<<dim3(NB), TB, 0, stream>>>(s2, x2, adj2, x3, scal);

    // MLP + output
    k_mlp<<<1, 512, 0, stream>>>(x3, Wf1, bf1, Wf2, bf2, scal, out);
}

// Round 7
// 419.927 us; speedup vs baseline: 1.1099x; 1.1099x over previous
//
#include <hip/hip_runtime.h>
#include <math.h>

#define NB 16
#define NPG 1024
#define DIN 16
#define ED 8
#define NHEADS 5
#define OUT1 6
#define HID 30
#define C1 32
#define C2 4
#define NN (NB*NPG)      // 16384 nodes
#define EE (NN*32)       // 524288 edges
#define EPG 32768        // edges per graph (graph-contiguous in edge_index)

__device__ __forceinline__ float lrelu(float v){ return v >= 0.f ? v : 0.2f*v; }

// XCD-affinity edge-chunk mapping: all blocks touching graph g land on XCD g%8
// (dispatch round-robins XCDs by blockIdx; performance-only heuristic).
// grid = 2048 blocks x 256 threads; returns first edge of this block's chunk.
__device__ __forceinline__ size_t xcd_chunk_base(){
    int x = blockIdx.x & 7;
    int j = blockIdx.x >> 3;            // 0..255 position within this XCD
    int g = x + 8*(j >> 7);             // 2 graphs per XCD
    int c = j & 127;                    // 128 chunks per graph
    return (size_t)g*EPG + (size_t)c*256;
}

// ---------- Stage 1 prep: h1 = x@W1 ; per-node attention scalars ----------
__global__ void k_node_proj1(const float* __restrict__ x, const float* __restrict__ W1,
                             const float* __restrict__ as1, const float* __restrict__ ad1,
                             float* __restrict__ h1, float* __restrict__ hs1, float* __restrict__ hd1){
    __shared__ float Ws[DIN*HID];
    __shared__ float as_s[HID], ad_s[HID];
    for (int i = threadIdx.x; i < DIN*HID; i += blockDim.x) Ws[i] = W1[i];
    if (threadIdx.x < HID){ as_s[threadIdx.x] = as1[threadIdx.x]; ad_s[threadIdx.x] = ad1[threadIdx.x]; }
    __syncthreads();
    int n = blockIdx.x*blockDim.x + threadIdx.x;
    if (n >= NN) return;
    float xv[DIN];
    #pragma unroll
    for (int i = 0; i < DIN; i++) xv[i] = x[n*DIN + i];
    float hv[HID];
    #pragma unroll
    for (int j = 0; j < HID; j++){
        float a = 0.f;
        #pragma unroll
        for (int i = 0; i < DIN; i++) a += xv[i]*Ws[i*HID + j];
        hv[j] = a; h1[(size_t)n*HID + j] = a;
    }
    #pragma unroll
    for (int h = 0; h < NHEADS; h++){
        float s = 0.f, d = 0.f;
        #pragma unroll
        for (int c = 0; c < OUT1; c++){ s += hv[h*OUT1+c]*as_s[h*OUT1+c]; d += hv[h*OUT1+c]*ad_s[h*OUT1+c]; }
        hs1[n*NHEADS + h] = s; hd1[n*NHEADS + h] = d;
    }
}

// ---------- both histograms in one pass (XCD-affine chunks) ----------
__global__ void k_hist2(const int* __restrict__ src, const int* __restrict__ dst,
                        int* __restrict__ deg, int* __restrict__ degS){
    size_t e = xcd_chunk_base() + threadIdx.x;
    atomicAdd(&deg[dst[e]], 1);
    atomicAdd(&degS[src[e]], 1);
}

__global__ void k_scan(const int* __restrict__ deg, int* __restrict__ rowptr){
    __shared__ int sums[1024];
    int t = threadIdx.x;
    int base = t*16;
    int loc[16];
    int s = 0;
    #pragma unroll
    for (int i = 0; i < 16; i++){ loc[i] = s; s += deg[base + i]; }
    sums[t] = s;
    __syncthreads();
    for (int off = 1; off < 1024; off <<= 1){
        int v = (t >= off) ? sums[t-off] : 0;
        __syncthreads();
        sums[t] += v;
        __syncthreads();
    }
    int excl = (t == 0) ? 0 : sums[t-1];
    #pragma unroll
    for (int i = 0; i < 16; i++) rowptr[base + i] = excl + loc[i];
    if (t == 1023) rowptr[NN] = sums[1023];
}

__global__ void k_fill2(const int* __restrict__ rowptr, const int* __restrict__ rowptrS,
                        int* __restrict__ fill, int* __restrict__ fillS){
    int n = blockIdx.x*blockDim.x + threadIdx.x;
    if (n < NN){ fill[n] = rowptr[n]; fillS[n] = rowptrS[n]; }
}

// dst-CSR: pos[e] = slot, srcs[slot] = src[e]   (for aggregations)
// src-CSR: nbrS[slot] = dst[e]                  (for T = A*S)
// XCD-affine chunks: fill-atomics and slot-writes for graph g stay on XCD g%8.
__global__ void k_scatter2(const int* __restrict__ src, const int* __restrict__ dst,
                           int* __restrict__ fill, int* __restrict__ fillS,
                           int* __restrict__ pos, int* __restrict__ srcs,
                           int* __restrict__ nbrS){
    size_t e = xcd_chunk_base() + threadIdx.x;
    int s = src[e], d = dst[e];
    int p = atomicAdd(&fill[d], 1);
    pos[e] = p; srcs[p] = s;
    int pS = atomicAdd(&fillS[s], 1);
    nbrS[pS] = d;
}

// ---------- edge-attr projections, written in CSR (dst-sorted) order ----------
__global__ void k_edge_proj(const float* __restrict__ ea, const float* __restrict__ We1,
                            const float* __restrict__ Wep1, const int* __restrict__ pos,
                            float* __restrict__ ew1s, float* __restrict__ ewp1s){
    __shared__ float W[ED*NHEADS];
    __shared__ float Wp[ED];
    if (threadIdx.x < ED*NHEADS) W[threadIdx.x] = We1[threadIdx.x];
    if (threadIdx.x < ED) Wp[threadIdx.x] = Wep1[threadIdx.x];
    __syncthreads();
    size_t e = xcd_chunk_base() + threadIdx.x;
    float a[ED];
    #pragma unroll
    for (int i = 0; i < ED; i++) a[i] = ea[e*ED + i];
    int p = pos[e];
    #pragma unroll
    for (int h = 0; h < NHEADS; h++){
        float s = 0.f;
        #pragma unroll
        for (int i = 0; i < ED; i++) s += a[i]*W[i*NHEADS + h];
        ew1s[(size_t)p*NHEADS + h] = s;
    }
    float s = 0.f;
    #pragma unroll
    for (int i = 0; i < ED; i++) s += a[i]*Wp[i];
    ewp1s[p] = s;
}

// ---------- dedup via per-thread LDS bitmap (neighbors are block-local 0..1023) ----------
__global__ void k_dedup(const int* __restrict__ rowptrS, const int* __restrict__ nbrS,
                        int* __restrict__ unbr, int* __restrict__ ucnt,
                        float* __restrict__ scal){
    __shared__ unsigned int bm[256*33];   // 33-word stride: bank = (t + w) & 31
    int t = threadIdx.x;
    unsigned int* mybm = &bm[t*33];
    #pragma unroll
    for (int i = 0; i < 32; i++) mybm[i] = 0u;
    int n = blockIdx.x*blockDim.x + t;
    int cnt = 0;
    if (n < NN){
        int k0 = rowptrS[n], k1 = rowptrS[n+1];
        for (int k = k0; k < k1; k++){
            int m = nbrS[k];
            int loc = m & (NPG-1);
            unsigned int w = (unsigned int)(loc >> 5);
            unsigned int bit = 1u << (loc & 31);
            unsigned int old = mybm[w];
            if (!(old & bit)){
                mybm[w] = old | bit;
                unbr[k0 + cnt] = m;
                cnt++;
            }
        }
        ucnt[n] = cnt;
    }
    __shared__ int red[256];
    red[t] = cnt; __syncthreads();
    for (int s = 128; s > 0; s >>= 1){ if (t < s) red[t] += red[t+s]; __syncthreads(); }
    if (t == 0) atomicAdd(&scal[0], (float)red[0]);
}

// ---------- conv1 aggregation: online softmax, one thread per (node, head) ----------
__global__ void k_conv1_agg(const int* __restrict__ srcs, const int* __restrict__ rowptr,
                            const float* __restrict__ h1,
                            const float* __restrict__ hs1, const float* __restrict__ hd1,
                            const float* __restrict__ ew1s, float* __restrict__ x1){
    int tid = blockIdx.x*blockDim.x + threadIdx.x;
    if (tid >= NN*NHEADS) return;
    int h = tid % NHEADS;
    int n = tid / NHEADS;
    int k0 = rowptr[n], k1 = rowptr[n+1];
    float hdv = hd1[n*NHEADS + h];
    float m = -INFINITY, den = 0.f;
    float acc[OUT1];
    #pragma unroll
    for (int c = 0; c < OUT1; c++) acc[c] = 0.f;
    for (int k = k0; k < k1; k++){
        int s = srcs[k];
        float l = lrelu(hs1[s*NHEADS + h] + hdv + ew1s[(size_t)k*NHEADS + h]);
        float mn = fmaxf(m, l);
        float f  = expf(m - mn);     // first iter: exp(-inf)=0
        float ex = expf(l - mn);
        m = mn;
        den = den*f + ex;
        const float* hr = h1 + (size_t)s*HID + h*OUT1;
        #pragma unroll
        for (int c = 0; c < OUT1; c++) acc[c] = acc[c]*f + ex*hr[c];
    }
    float inv = 1.f / (den + 1e-16f);
    #pragma unroll
    for (int c = 0; c < OUT1; c++) x1[(size_t)n*HID + h*OUT1 + c] = acc[c]*inv;
}

// ---------- pool-conv1 prep: hp1 = x1@Wp1 (30x32); scalars ----------
__global__ void k_node_proj_p1(const float* __restrict__ x1, const float* __restrict__ Wp1,
                               const float* __restrict__ asp, const float* __restrict__ adp,
                               float* __restrict__ hp1, float* __restrict__ hsp, float* __restrict__ hdp){
    __shared__ float Ws[HID*C1];
    __shared__ float as_s[C1], ad_s[C1];
    for (int i = threadIdx.x; i < HID*C1; i += blockDim.x) Ws[i] = Wp1[i];
    if (threadIdx.x < C1){ as_s[threadIdx.x] = asp[threadIdx.x]; ad_s[threadIdx.x] = adp[threadIdx.x]; }
    __syncthreads();
    int n = blockIdx.x*blockDim.x + threadIdx.x;
    if (n >= NN) return;
    float xv[HID];
    #pragma unroll
    for (int d = 0; d < HID; d++) xv[d] = x1[(size_t)n*HID + d];
    float s = 0.f, dd = 0.f;
    for (int c = 0; c < C1; c++){
        float a = 0.f;
        #pragma unroll
        for (int d = 0; d < HID; d++) a += xv[d]*Ws[d*C1 + c];
        hp1[(size_t)n*C1 + c] = a;
        s += a*as_s[c]; dd += a*ad_s[c];
    }
    hsp[n] = s; hdp[n] = dd;
}

// ---------- pool-conv1 aggregation: online softmax, thread per (node, 8-ch quarter) ----------
__global__ void k_pool1_agg(const int* __restrict__ srcs, const int* __restrict__ rowptr,
                            const float* __restrict__ hp1,
                            const float* __restrict__ hsp, const float* __restrict__ hdp,
                            const float* __restrict__ ewp1s, float* __restrict__ s1){
    int tid = blockIdx.x*blockDim.x + threadIdx.x;
    if (tid >= NN*4) return;
    int q = tid & 3;
    int n = tid >> 2;
    int k0 = rowptr[n], k1 = rowptr[n+1];
    float hdv = hdp[n];
    float m = -INFINITY, den = 0.f;
    float acc[8];
    #pragma unroll
    for (int c = 0; c < 8; c++) acc[c] = 0.f;
    for (int k = k0; k < k1; k++){
        int s = srcs[k];
        float l = lrelu(hsp[s] + hdv + ewp1s[k]);
        float mn = fmaxf(m, l);
        float f  = expf(m - mn);
        float ex = expf(l - mn);
        m = mn;
        den = den*f + ex;
        const float* hr = hp1 + (size_t)s*C1 + q*8;
        #pragma unroll
        for (int c = 0; c < 8; c++) acc[c] = acc[c]*f + ex*hr[c];
    }
    float inv = 1.f / (den + 1e-16f);
    #pragma unroll
    for (int c = 0; c < 8; c++) s1[(size_t)n*C1 + q*8 + c] = acc[c]*inv;
}

// ---------- cluster softmax (over 32) ----------
__global__ void k_soft32(const float* __restrict__ s1, float* __restrict__ ssoft){
    int n = blockIdx.x*blockDim.x + threadIdx.x;
    if (n >= NN) return;
    float v[C1];
    float m = -INFINITY;
    #pragma unroll
    for (int c = 0; c < C1; c++){ v[c] = s1[(size_t)n*C1 + c]; m = fmaxf(m, v[c]); }
    float sum = 0.f;
    #pragma unroll
    for (int c = 0; c < C1; c++){ v[c] = expf(v[c] - m); sum += v[c]; }
    float inv = 1.f/sum;
    #pragma unroll
    for (int c = 0; c < C1; c++) ssoft[(size_t)n*C1 + c] = v[c]*inv;
}

// ---------- T[n,:] = sum over unique out-neighbors m of S[m,:] ----------
__global__ void k_T(const int* __restrict__ rowptrS, const int* __restrict__ unbr,
                    const int* __restrict__ ucnt, const float* __restrict__ ssoft,
                    float* __restrict__ T){
    int tid = blockIdx.x*blockDim.x + threadIdx.x;
    if (tid >= NN*4) return;
    int q = tid & 3;
    int n = tid >> 2;
    int k0 = rowptrS[n];
    int cnt = ucnt[n];
    float acc[8];
    #pragma unroll
    for (int c = 0; c < 8; c++) acc[c] = 0.f;
    for (int i = 0; i < cnt; i++){
        int m = unbr[k0 + i];
        const float* sr = ssoft + (size_t)m*C1 + q*8;
        #pragma unroll
        for (int c = 0; c < 8; c++) acc[c] += sr[c];
    }
    #pragma unroll
    for (int c = 0; c < 8; c++) T[(size_t)n*C1 + q*8 + c] = acc[c];
}

// ---------- fused partials over 64-node chunks:
//   adj2 += S_chunk^T T_chunk ; G += S_chunk^T S_chunk ; x2 += S_chunk^T X_chunk
__global__ void k_partials(const float* __restrict__ ssoft, const float* __restrict__ T,
                           const float* __restrict__ x1,
                           float* __restrict__ adj2, float* __restrict__ Gm,
                           float* __restrict__ x2){
    int b  = blockIdx.y;
    int n0 = blockIdx.x * 64;
    int t  = threadIdx.x;   // 256
    __shared__ float ssh[64*C1];
    __shared__ float tsh[64*C1];
    __shared__ float xsh[64*HID];
    {
        size_t sbase = ((size_t)b*NPG + n0)*C1;
        #pragma unroll
        for (int i = 0; i < 8; i++){
            int lin = t + i*256;
            ssh[lin] = ssoft[sbase + lin];
            tsh[lin] = T[sbase + lin];
        }
        size_t xbase = ((size_t)b*NPG + n0)*HID;
        for (int lin = t; lin < 64*HID; lin += 256) xsh[lin] = x1[xbase + lin];
    }
    __syncthreads();
    float accA[4] = {0,0,0,0}, accG[4] = {0,0,0,0}, accX[4] = {0,0,0,0};
    int cA[4], kA[4], cX[4], dX[4];
    #pragma unroll
    for (int q = 0; q < 4; q++){
        int p = t + q*256;
        cA[q] = p >> 5; kA[q] = p & 31;
        cX[q] = p / HID; dX[q] = p - cX[q]*HID;   // valid only when p < 960
    }
    for (int r = 0; r < 64; r++){
        const float* sr = ssh + r*C1;
        const float* tr = tsh + r*C1;
        const float* xr = xsh + r*HID;
        #pragma unroll
        for (int q = 0; q < 4; q++){
            float sc = sr[cA[q]];
            accA[q] += sc*tr[kA[q]];
            accG[q] += sc*sr[kA[q]];
        }
        #pragma unroll
        for (int q = 0; q < 4; q++){
            int p = t + q*256;
            if (p < C1*HID) accX[q] += sr[cX[q]]*xr[dX[q]];
        }
    }
    #pragma unroll
    for (int q = 0; q < 4; q++){
        int p = t + q*256;
        atomicAdd(&adj2[(size_t)b*1024 + p], accA[q]);
        atomicAdd(&Gm[(size_t)b*1024 + p], accG[q]);
        if (p < C1*HID) atomicAdd(&x2[((size_t)b*C1 + cX[q])*HID + dX[q]], accX[q]);
    }
}

// ---------- finalize reg1 ingredients: trace(adj2), ||G||_F^2 ----------
__global__ void k_finalize(const float* __restrict__ adj2, const float* __restrict__ Gm,
                           float* __restrict__ scal){
    int b = blockIdx.x;
    int t = threadIdx.x;   // 256
    float ltr = 0.f, lfr = 0.f;
    for (int p = t; p < 1024; p += 256){
        float g = Gm[(size_t)b*1024 + p];
        lfr += g*g;
        if ((p >> 5) == (p & 31)) ltr += adj2[(size_t)b*1024 + p];
    }
    __shared__ float red[256];
    red[t] = ltr; __syncthreads();
    for (int s = 128; s > 0; s >>= 1){ if (t < s) red[t] += red[t+s]; __syncthreads(); }
    if (t == 0) atomicAdd(&scal[1], red[0]);
    __syncthreads();
    red[t] = lfr; __syncthreads();
    for (int s = 128; s > 0; s >>= 1){ if (t < s) red[t] += red[t+s]; __syncthreads(); }
    if (t == 0) atomicAdd(&scal[2], red[0]);
}

// ---------- pool-conv2 prep ----------
__global__ void k_node_proj2(const float* __restrict__ x2, const float* __restrict__ Wp2,
                             const float* __restrict__ asp, const float* __restrict__ adp,
                             float* __restrict__ h2, float* __restrict__ hs2, float* __restrict__ hd2){
    __shared__ float Ws[HID*C2];
    __shared__ float as_s[C2], ad_s[C2];
    for (int i = threadIdx.x; i < HID*C2; i += blockDim.x) Ws[i] = Wp2[i];
    if (threadIdx.x < C2){ as_s[threadIdx.x] = asp[threadIdx.x]; ad_s[threadIdx.x] = adp[threadIdx.x]; }
    __syncthreads();
    int n = blockIdx.x*blockDim.x + threadIdx.x;
    if (n >= NB*C1) return;
    float xv[HID];
    #pragma unroll
    for (int d = 0; d < HID; d++) xv[d] = x2[(size_t)n*HID + d];
    float s = 0.f, dd = 0.f;
    #pragma unroll
    for (int c = 0; c < C2; c++){
        float a = 0.f;
        #pragma unroll
        for (int d = 0; d < HID; d++) a += xv[d]*Ws[d*C2 + c];
        h2[n*C2 + c] = a;
        s += a*as_s[c]; dd += a*ad_s[c];
    }
    hs2[n] = s; hd2[n] = dd;
}

// ---------- pool-conv2 aggregation (dense 32-in per dst, attr = adj2) ----------
__global__ void k_pool2_agg(const float* __restrict__ h2, const float* __restrict__ hs2,
                            const float* __restrict__ hd2, const float* __restrict__ adj2,
                            const float* __restrict__ Wep2, float* __restrict__ s2){
    int n = blockIdx.x*blockDim.x + threadIdx.x;   // dst node, 0..511
    if (n >= NB*C1) return;
    int b = n >> 5, j = n & 31;
    float hdv = hd2[n];
    float wep = Wep2[0];
    float m = -INFINITY;
    for (int i = 0; i < C1; i++){
        float l = lrelu(hs2[b*C1 + i] + hdv + adj2[(size_t)b*1024 + i*32 + j]*wep);
        m = fmaxf(m, l);
    }
    float den = 0.f;
    float acc[C2] = {0,0,0,0};
    for (int i = 0; i < C1; i++){
        float l = lrelu(hs2[b*C1 + i] + hdv + adj2[(size_t)b*1024 + i*32 + j]*wep);
        float ex = expf(l - m);
        den += ex;
        #pragma unroll
        for (int c = 0; c < C2; c++) acc[c] += ex * h2[(b*C1 + i)*C2 + c];
    }
    float inv = 1.f/(den + 1e-16f);
    #pragma unroll
    for (int c = 0; c < C2; c++) s2[n*C2 + c] = acc[c]*inv;
}

// ---------- diffpool2: softmax(s2), x3 = S^T x2, reg2 ----------
__global__ void k_pool2(const float* __restrict__ s2, const float* __restrict__ x2,
                        const float* __restrict__ adj2, float* __restrict__ x3,
                        float* __restrict__ scal){
    int b = blockIdx.x;
    int t = threadIdx.x;  // 256
    __shared__ float ss[C1*C2];
    __shared__ float xs[C1*HID];
    if (t < C1){
        float v[C2]; float m = -INFINITY;
        #pragma unroll
        for (int c = 0; c < C2; c++){ v[c] = s2[(b*C1 + t)*C2 + c]; m = fmaxf(m, v[c]); }
        float sum = 0.f;
        #pragma unroll
        for (int c = 0; c < C2; c++){ v[c] = expf(v[c] - m); sum += v[c]; }
        float inv = 1.f/sum;
        #pragma unroll
        for (int c = 0; c < C2; c++) ss[t*C2 + c] = v[c]*inv;
    }
    for (int lin = t; lin < C1*HID; lin += 256) xs[lin] = x2[(size_t)b*C1*HID + lin];
    __syncthreads();
    if (t < C2*HID){
        int c = t / HID, d = t % HID;
        float a = 0.f;
        #pragma unroll
        for (int n = 0; n < C1; n++) a += ss[n*C2 + c]*xs[n*HID + d];
        x3[(size_t)b*C2*HID + t] = a;
    }
    float loc = 0.f;
    for (int p = t; p < 1024; p += 256){
        int n = p >> 5, mm = p & 31;
        float dot = 0.f;
        #pragma unroll
        for (int c = 0; c < C2; c++) dot += ss[n*C2 + c]*ss[mm*C2 + c];
        float df = adj2[(size_t)b*1024 + p] - dot;
        loc += df*df;
    }
    __shared__ float red[256];
    red[t] = loc; __syncthreads();
    for (int s = 128; s > 0; s >>= 1){ if (t < s) red[t] += red[t+s]; __syncthreads(); }
    if (t == 0) atomicAdd(&scal[3], red[0]);
}

// ---------- final MLP + reg assembly ----------
__global__ void k_mlp(const float* __restrict__ x3, const float* __restrict__ Wf1,
                      const float* __restrict__ bf1, const float* __restrict__ Wf2,
                      const float* __restrict__ bf2, const float* __restrict__ scal,
                      float* __restrict__ out){
    __shared__ float zsh[NB*32];
    int t = threadIdx.x;   // 512
    if (t < NB*32){
        int b = t >> 5, j = t & 31;
        float a = bf1[j];
        const float* xr = x3 + (size_t)b*C2*HID;
        #pragma unroll 4
        for (int k = 0; k < C2*HID; k++) a += xr[k]*Wf1[k*32 + j];
        zsh[t] = fmaxf(a, 0.f);
    }
    __syncthreads();
    if (t < NB*2){
        int b = t >> 1, o = t & 1;
        float a = bf2[o];
        #pragma unroll
        for (int j = 0; j < 32; j++) a += zsh[b*32 + j]*Wf2[j*2 + o];
        out[t] = a;
    }
    if (t == 0){
        float adjsum = scal[0], tr = scal[1], fr = scal[2], r2 = scal[3];
        float reg1 = (adjsum - 2.f*tr + fr) * (1.f/16777216.f);
        float reg2 = r2 * (1.f/16384.f);
        out[32] = 10.f*reg1 + 0.1f*reg2;
    }
}

extern "C" void kernel_launch(void* const* d_in, const int* in_sizes, int n_in,
                              void* d_out, int out_size, void* d_ws, size_t ws_size,
                              hipStream_t stream) {
    const float* x    = (const float*)d_in[0];
    const int*   ei   = (const int*)d_in[1];
    const float* ea   = (const float*)d_in[2];
    // d_in[3] = y (unused); d_in[4] = adj (algebraically eliminated — never read)
    const float* W1   = (const float*)d_in[5];
    const float* as1  = (const float*)d_in[6];
    const float* ad1  = (const float*)d_in[7];
    const float* We1  = (const float*)d_in[8];
    const float* Wp1  = (const float*)d_in[9];
    const float* asp1 = (const float*)d_in[10];
    const float* adp1 = (const float*)d_in[11];
    const float* Wep1 = (const float*)d_in[12];
    const float* Wp2  = (const float*)d_in[13];
    const float* asp2 = (const float*)d_in[14];
    const float* adp2 = (const float*)d_in[15];
    const float* Wep2 = (const float*)d_in[16];
    const float* Wf1  = (const float*)d_in[17];
    const float* bf1  = (const float*)d_in[18];
    const float* Wf2  = (const float*)d_in[19];
    const float* bf2  = (const float*)d_in[20];
    float* out = (float*)d_out;

    const int* srcA = ei;
    const int* dstA = ei + EE;

    char* wp = (char*)d_ws;
    auto carve = [&](size_t bytes)->char*{
        char* p = wp;
        wp += (bytes + 255) & ~(size_t)255;
        return p;
    };
    float* h1    = (float*)carve((size_t)NN*HID*4);
    float* hs1   = (float*)carve((size_t)NN*NHEADS*4);
    float* hd1   = (float*)carve((size_t)NN*NHEADS*4);
    float* ew1s  = (float*)carve((size_t)EE*NHEADS*4);
    float* ewp1s = (float*)carve((size_t)EE*4);
    float* x1    = (float*)carve((size_t)NN*HID*4);
    float* hp1   = (float*)carve((size_t)NN*C1*4);
    float* hsp   = (float*)carve((size_t)NN*4);
    float* hdp   = (float*)carve((size_t)NN*4);
    float* s1    = (float*)carve((size_t)NN*C1*4);
    float* ssoft = (float*)carve((size_t)NN*C1*4);
    float* T     = (float*)carve((size_t)NN*C1*4);
    // --- zero-init region (contiguous): x2, adj2, Gm ---
    float* x2    = (float*)carve((size_t)NB*C1*HID*4);   // 61440 B (256-aligned)
    float* adj2  = (float*)carve((size_t)NB*C1*C1*4);    // 65536 B
    float* Gm    = (float*)carve((size_t)NB*C1*C1*4);    // 65536 B
    // ---------------------------------------------------
    float* h2    = (float*)carve((size_t)NB*C1*C2*4);
    float* hs2   = (float*)carve((size_t)NB*C1*4);
    float* hd2   = (float*)carve((size_t)NB*C1*4);
    float* s2    = (float*)carve((size_t)NB*C1*C2*4);
    float* x3    = (float*)carve((size_t)NB*C2*HID*4);
    float* scal  = (float*)carve(16*4);
    // --- zero-init region (contiguous): deg, degS ---
    int* deg     = (int*)carve((size_t)NN*4);
    int* degS    = (int*)carve((size_t)NN*4);
    // ------------------------------------------------
    int* rowptr  = (int*)carve((size_t)(NN+1)*4);
    int* rowptrS = (int*)carve((size_t)(NN+1)*4);
    int* fill    = (int*)carve((size_t)NN*4);
    int* fillS   = (int*)carve((size_t)NN*4);
    int* pos     = (int*)carve((size_t)EE*4);
    int* srcs    = (int*)carve((size_t)EE*4);
    int* nbrS    = (int*)carve((size_t)EE*4);
    int* unbr    = (int*)carve((size_t)EE*4);
    int* ucnt    = (int*)carve((size_t)NN*4);

    hipMemsetAsync(deg, 0, (size_t)2*NN*4, stream);        // deg + degS contiguous
    hipMemsetAsync(scal, 0, 16*4, stream);
    hipMemsetAsync(x2, 0, (size_t)(NB*C1*HID + 2*NB*C1*C1)*4, stream);  // x2+adj2+Gm

    const int TB = 256;
    dim3 gN((NN + TB - 1)/TB), gE(EE/TB);   // gE = 2048 (exact)

    // node projection (independent of graph structure)
    k_node_proj1<<<gN, TB, 0, stream>>>(x, W1, as1, ad1, h1, hs1, hd1);

    // dual CSR build (XCD-affine edge chunks)
    k_hist2<<<gE, TB, 0, stream>>>(srcA, dstA, deg, degS);
    k_scan<<<1, 1024, 0, stream>>>(deg, rowptr);
    k_scan<<<1, 1024, 0, stream>>>(degS, rowptrS);
    k_fill2<<<gN, TB, 0, stream>>>(rowptr, rowptrS, fill, fillS);
    k_scatter2<<<gE, TB, 0, stream>>>(srcA, dstA, fill, fillS, pos, srcs, nbrS);

    // dedup unique out-neighbors via LDS bitmap + sum(A)
    k_dedup<<<dim3(NN/TB), TB, 0, stream>>>(rowptrS, nbrS, unbr, ucnt, scal);

    // edge projections written in CSR order (XCD-affine chunks)
    k_edge_proj<<<gE, TB, 0, stream>>>(ea, We1, Wep1, pos, ew1s, ewp1s);

    // conv1: thread per (node, head), single-pass online softmax
    k_conv1_agg<<<dim3((NN*NHEADS + TB - 1)/TB), TB, 0, stream>>>(srcs, rowptr, h1, hs1, hd1, ew1s, x1);

    // pool-conv1
    k_node_proj_p1<<<gN, TB, 0, stream>>>(x1, Wp1, asp1, adp1, hp1, hsp, hdp);
    k_pool1_agg<<<dim3((NN*4 + TB - 1)/TB), TB, 0, stream>>>(srcs, rowptr, hp1, hsp, hdp, ewp1s, s1);

    // diffpool1
    k_soft32<<<gN, TB, 0, stream>>>(s1, ssoft);
    k_T<<<dim3((NN*4 + TB - 1)/TB), TB, 0, stream>>>(rowptrS, unbr, ucnt, ssoft, T);
    k_partials<<<dim3(16, NB), TB, 0, stream>>>(ssoft, T, x1, adj2, Gm, x2);
    k_finalize<<<dim3(NB), TB, 0, stream>>>(adj2, Gm, scal);

    // pool-conv2 on dense pooled graph
    k_node_proj2<<<dim3(2), TB, 0, stream>>>(x2, Wp2, asp2, adp2, h2, hs2, hd2);
    k_pool2_agg<<<dim3(2), TB, 0, stream>>>(h2, hs2, hd2, adj2, Wep2, s2);

    // diffpool2 + reg2
    k_pool2<<<dim3(NB), TB, 0, stream>>>(s2, x2, adj2, x3, scal);

    // MLP + output
    k_mlp<<<1, 512, 0, stream>>>(x3, Wf1, bf1, Wf2, bf2, scal, out);
}

// Round 8
// 414.177 us; speedup vs baseline: 1.1253x; 1.0139x over previous
//
#include <hip/hip_runtime.h>
#include <math.h>

#define NB 16
#define NPG 1024
#define DIN 16
#define ED 8
#define NHEADS 5
#define OUT1 6
#define HID 30
#define C1 32
#define C2 4
#define NN (NB*NPG)      // 16384 nodes
#define EE (NN*32)       // 524288 edges
#define EPG 32768        // edges per graph (graph-contiguous in edge_index)

__device__ __forceinline__ float lrelu(float v){ return v >= 0.f ? v : 0.2f*v; }

// XCD-affinity edge-chunk mapping: all blocks touching graph g land on XCD g%8
// (dispatch round-robins XCDs by blockIdx; performance-only heuristic).
// grid = 2048 blocks x 256 threads; returns first edge/slot of this block's chunk.
__device__ __forceinline__ size_t xcd_chunk_base(){
    int x = blockIdx.x & 7;
    int j = blockIdx.x >> 3;            // 0..255 position within this XCD
    int g = x + 8*(j >> 7);             // 2 graphs per XCD
    int c = j & 127;                    // 128 chunks per graph
    return (size_t)g*EPG + (size_t)c*256;
}

// ---------- Stage 1 prep: h1 = x@W1 ; per-node attention scalars ----------
__global__ void k_node_proj1(const float* __restrict__ x, const float* __restrict__ W1,
                             const float* __restrict__ as1, const float* __restrict__ ad1,
                             float* __restrict__ h1, float* __restrict__ hs1, float* __restrict__ hd1){
    __shared__ float Ws[DIN*HID];
    __shared__ float as_s[HID], ad_s[HID];
    for (int i = threadIdx.x; i < DIN*HID; i += blockDim.x) Ws[i] = W1[i];
    if (threadIdx.x < HID){ as_s[threadIdx.x] = as1[threadIdx.x]; ad_s[threadIdx.x] = ad1[threadIdx.x]; }
    __syncthreads();
    int n = blockIdx.x*blockDim.x + threadIdx.x;
    if (n >= NN) return;
    float xv[DIN];
    #pragma unroll
    for (int i = 0; i < DIN; i++) xv[i] = x[n*DIN + i];
    float hv[HID];
    #pragma unroll
    for (int j = 0; j < HID; j++){
        float a = 0.f;
        #pragma unroll
        for (int i = 0; i < DIN; i++) a += xv[i]*Ws[i*HID + j];
        hv[j] = a; h1[(size_t)n*HID + j] = a;
    }
    #pragma unroll
    for (int h = 0; h < NHEADS; h++){
        float s = 0.f, d = 0.f;
        #pragma unroll
        for (int c = 0; c < OUT1; c++){ s += hv[h*OUT1+c]*as_s[h*OUT1+c]; d += hv[h*OUT1+c]*ad_s[h*OUT1+c]; }
        hs1[n*NHEADS + h] = s; hd1[n*NHEADS + h] = d;
    }
}

// ---------- both histograms in one pass (XCD-affine chunks) ----------
__global__ void k_hist2(const int* __restrict__ src, const int* __restrict__ dst,
                        int* __restrict__ deg, int* __restrict__ degS){
    size_t e = xcd_chunk_base() + threadIdx.x;
    atomicAdd(&deg[dst[e]], 1);
    atomicAdd(&degS[src[e]], 1);
}

// ---------- both exclusive scans + fill copies: 2 blocks, wave-shfl scan ----------
__global__ __launch_bounds__(1024) void k_scan2f(const int* __restrict__ deg,
                        const int* __restrict__ degS,
                        int* __restrict__ rowptr, int* __restrict__ rowptrS,
                        int* __restrict__ fill, int* __restrict__ fillS){
    __shared__ int wtot[16];
    __shared__ int wbase[16];
    const int* d = (blockIdx.x == 0) ? deg    : degS;
    int* rp      = (blockIdx.x == 0) ? rowptr : rowptrS;
    int* fl      = (blockIdx.x == 0) ? fill   : fillS;
    int t = threadIdx.x;
    int lane = t & 63, wv = t >> 6;
    int base = t*16;
    int loc[16]; int tot = 0;
    #pragma unroll
    for (int i = 0; i < 16; i++){ loc[i] = tot; tot += d[base + i]; }
    int sincl = tot;                       // wave-inclusive scan of thread totals
    #pragma unroll
    for (int off = 1; off < 64; off <<= 1){
        int v = __shfl_up(sincl, off, 64);
        if (lane >= off) sincl += v;
    }
    if (lane == 63) wtot[wv] = sincl;
    __syncthreads();
    if (t == 0){
        int run = 0;
        #pragma unroll
        for (int w = 0; w < 16; w++){ wbase[w] = run; run += wtot[w]; }
    }
    __syncthreads();
    int gexcl = wbase[wv] + sincl - tot;   // global exclusive prefix for this thread
    #pragma unroll
    for (int i = 0; i < 16; i++){
        int v = gexcl + loc[i];
        rp[base + i] = v;
        fl[base + i] = v;
    }
    if (t == 1023) rp[NN] = gexcl + tot;
}

// dst-CSR: se[slot] = (src[e], e)   (for aggregations + edge projection)
// src-CSR: nbrS[slot] = dst[e]      (for dedup / T = A*S)
__global__ void k_scatter2(const int* __restrict__ src, const int* __restrict__ dst,
                           int* __restrict__ fill, int* __restrict__ fillS,
                           int2* __restrict__ se, int* __restrict__ nbrS){
    size_t e = xcd_chunk_base() + threadIdx.x;
    int s = src[e], d = dst[e];
    int p = atomicAdd(&fill[d], 1);
    se[p] = make_int2(s, (int)e);
    int pS = atomicAdd(&fillS[s], 1);
    nbrS[pS] = d;
}

// ---------- edge-attr projections over CSR slots: coalesced writes, L2 gathers ----------
__global__ void k_edge_proj(const float* __restrict__ ea, const float* __restrict__ We1,
                            const float* __restrict__ Wep1, const int2* __restrict__ se,
                            float* __restrict__ ew1s, float* __restrict__ ewp1s){
    __shared__ float W[ED*NHEADS];
    __shared__ float Wp[ED];
    if (threadIdx.x < ED*NHEADS) W[threadIdx.x] = We1[threadIdx.x];
    if (threadIdx.x < ED) Wp[threadIdx.x] = Wep1[threadIdx.x];
    __syncthreads();
    size_t k = xcd_chunk_base() + threadIdx.x;
    int e = se[k].y;
    float a[ED];
    #pragma unroll
    for (int i = 0; i < ED; i++) a[i] = ea[(size_t)e*ED + i];
    #pragma unroll
    for (int h = 0; h < NHEADS; h++){
        float s = 0.f;
        #pragma unroll
        for (int i = 0; i < ED; i++) s += a[i]*W[i*NHEADS + h];
        ew1s[k*NHEADS + h] = s;
    }
    float s = 0.f;
    #pragma unroll
    for (int i = 0; i < ED; i++) s += a[i]*Wp[i];
    ewp1s[k] = s;
}

// ---------- dedup via per-thread LDS bitmap (neighbors are block-local 0..1023) ----------
__global__ void k_dedup(const int* __restrict__ rowptrS, const int* __restrict__ nbrS,
                        int* __restrict__ unbr, int* __restrict__ ucnt,
                        float* __restrict__ scal){
    __shared__ unsigned int bm[256*33];   // 33-word stride: bank = (t + w) & 31
    int t = threadIdx.x;
    unsigned int* mybm = &bm[t*33];
    #pragma unroll
    for (int i = 0; i < 32; i++) mybm[i] = 0u;
    int n = blockIdx.x*blockDim.x + t;
    int cnt = 0;
    if (n < NN){
        int k0 = rowptrS[n], k1 = rowptrS[n+1];
        for (int k = k0; k < k1; k++){
            int m = nbrS[k];
            int loc = m & (NPG-1);
            unsigned int w = (unsigned int)(loc >> 5);
            unsigned int bit = 1u << (loc & 31);
            unsigned int old = mybm[w];
            if (!(old & bit)){
                mybm[w] = old | bit;
                unbr[k0 + cnt] = m;
                cnt++;
            }
        }
        ucnt[n] = cnt;
    }
    __shared__ int red[256];
    red[t] = cnt; __syncthreads();
    for (int s = 128; s > 0; s >>= 1){ if (t < s) red[t] += red[t+s]; __syncthreads(); }
    if (t == 0) atomicAdd(&scal[0], (float)red[0]);
}

// ---------- conv1 aggregation: online softmax, one thread per (node, head) ----------
__global__ void k_conv1_agg(const int2* __restrict__ se, const int* __restrict__ rowptr,
                            const float* __restrict__ h1,
                            const float* __restrict__ hs1, const float* __restrict__ hd1,
                            const float* __restrict__ ew1s, float* __restrict__ x1){
    int tid = blockIdx.x*blockDim.x + threadIdx.x;
    if (tid >= NN*NHEADS) return;
    int h = tid % NHEADS;
    int n = tid / NHEADS;
    int k0 = rowptr[n], k1 = rowptr[n+1];
    float hdv = hd1[n*NHEADS + h];
    float m = -INFINITY, den = 0.f;
    float acc[OUT1];
    #pragma unroll
    for (int c = 0; c < OUT1; c++) acc[c] = 0.f;
    for (int k = k0; k < k1; k++){
        int s = se[k].x;
        float l = lrelu(hs1[s*NHEADS + h] + hdv + ew1s[(size_t)k*NHEADS + h]);
        float mn = fmaxf(m, l);
        float f  = expf(m - mn);     // first iter: exp(-inf)=0
        float ex = expf(l - mn);
        m = mn;
        den = den*f + ex;
        const float* hr = h1 + (size_t)s*HID + h*OUT1;
        #pragma unroll
        for (int c = 0; c < OUT1; c++) acc[c] = acc[c]*f + ex*hr[c];
    }
    float inv = 1.f / (den + 1e-16f);
    #pragma unroll
    for (int c = 0; c < OUT1; c++) x1[(size_t)n*HID + h*OUT1 + c] = acc[c]*inv;
}

// ---------- pool-conv1 prep: hp1 = x1@Wp1 (30x32); scalars ----------
__global__ void k_node_proj_p1(const float* __restrict__ x1, const float* __restrict__ Wp1,
                               const float* __restrict__ asp, const float* __restrict__ adp,
                               float* __restrict__ hp1, float* __restrict__ hsp, float* __restrict__ hdp){
    __shared__ float Ws[HID*C1];
    __shared__ float as_s[C1], ad_s[C1];
    for (int i = threadIdx.x; i < HID*C1; i += blockDim.x) Ws[i] = Wp1[i];
    if (threadIdx.x < C1){ as_s[threadIdx.x] = asp[threadIdx.x]; ad_s[threadIdx.x] = adp[threadIdx.x]; }
    __syncthreads();
    int n = blockIdx.x*blockDim.x + threadIdx.x;
    if (n >= NN) return;
    float xv[HID];
    #pragma unroll
    for (int d = 0; d < HID; d++) xv[d] = x1[(size_t)n*HID + d];
    float s = 0.f, dd = 0.f;
    for (int c = 0; c < C1; c++){
        float a = 0.f;
        #pragma unroll
        for (int d = 0; d < HID; d++) a += xv[d]*Ws[d*C1 + c];
        hp1[(size_t)n*C1 + c] = a;
        s += a*as_s[c]; dd += a*ad_s[c];
    }
    hsp[n] = s; hdp[n] = dd;
}

// ---------- pool-conv1 aggregation: online softmax, thread per (node, 8-ch quarter) ----------
__global__ void k_pool1_agg(const int2* __restrict__ se, const int* __restrict__ rowptr,
                            const float* __restrict__ hp1,
                            const float* __restrict__ hsp, const float* __restrict__ hdp,
                            const float* __restrict__ ewp1s, float* __restrict__ s1){
    int tid = blockIdx.x*blockDim.x + threadIdx.x;
    if (tid >= NN*4) return;
    int q = tid & 3;
    int n = tid >> 2;
    int k0 = rowptr[n], k1 = rowptr[n+1];
    float hdv = hdp[n];
    float m = -INFINITY, den = 0.f;
    float acc[8];
    #pragma unroll
    for (int c = 0; c < 8; c++) acc[c] = 0.f;
    for (int k = k0; k < k1; k++){
        int s = se[k].x;
        float l = lrelu(hsp[s] + hdv + ewp1s[k]);
        float mn = fmaxf(m, l);
        float f  = expf(m - mn);
        float ex = expf(l - mn);
        m = mn;
        den = den*f + ex;
        const float* hr = hp1 + (size_t)s*C1 + q*8;
        #pragma unroll
        for (int c = 0; c < 8; c++) acc[c] = acc[c]*f + ex*hr[c];
    }
    float inv = 1.f / (den + 1e-16f);
    #pragma unroll
    for (int c = 0; c < 8; c++) s1[(size_t)n*C1 + q*8 + c] = acc[c]*inv;
}

// ---------- cluster softmax (over 32) ----------
__global__ void k_soft32(const float* __restrict__ s1, float* __restrict__ ssoft){
    int n = blockIdx.x*blockDim.x + threadIdx.x;
    if (n >= NN) return;
    float v[C1];
    float m = -INFINITY;
    #pragma unroll
    for (int c = 0; c < C1; c++){ v[c] = s1[(size_t)n*C1 + c]; m = fmaxf(m, v[c]); }
    float sum = 0.f;
    #pragma unroll
    for (int c = 0; c < C1; c++){ v[c] = expf(v[c] - m); sum += v[c]; }
    float inv = 1.f/sum;
    #pragma unroll
    for (int c = 0; c < C1; c++) ssoft[(size_t)n*C1 + c] = v[c]*inv;
}

// ---------- T[n,:] = sum over unique out-neighbors m of S[m,:] ----------
__global__ void k_T(const int* __restrict__ rowptrS, const int* __restrict__ unbr,
                    const int* __restrict__ ucnt, const float* __restrict__ ssoft,
                    float* __restrict__ T){
    int tid = blockIdx.x*blockDim.x + threadIdx.x;
    if (tid >= NN*4) return;
    int q = tid & 3;
    int n = tid >> 2;
    int k0 = rowptrS[n];
    int cnt = ucnt[n];
    float acc[8];
    #pragma unroll
    for (int c = 0; c < 8; c++) acc[c] = 0.f;
    for (int i = 0; i < cnt; i++){
        int m = unbr[k0 + i];
        const float* sr = ssoft + (size_t)m*C1 + q*8;
        #pragma unroll
        for (int c = 0; c < 8; c++) acc[c] += sr[c];
    }
    #pragma unroll
    for (int c = 0; c < 8; c++) T[(size_t)n*C1 + q*8 + c] = acc[c];
}

// ---------- fused partials over 64-node chunks:
//   adj2 += S_chunk^T T_chunk ; G += S_chunk^T S_chunk ; x2 += S_chunk^T X_chunk
__global__ void k_partials(const float* __restrict__ ssoft, const float* __restrict__ T,
                           const float* __restrict__ x1,
                           float* __restrict__ adj2, float* __restrict__ Gm,
                           float* __restrict__ x2){
    int b  = blockIdx.y;
    int n0 = blockIdx.x * 64;
    int t  = threadIdx.x;   // 256
    __shared__ float ssh[64*C1];
    __shared__ float tsh[64*C1];
    __shared__ float xsh[64*HID];
    {
        size_t sbase = ((size_t)b*NPG + n0)*C1;
        #pragma unroll
        for (int i = 0; i < 8; i++){
            int lin = t + i*256;
            ssh[lin] = ssoft[sbase + lin];
            tsh[lin] = T[sbase + lin];
        }
        size_t xbase = ((size_t)b*NPG + n0)*HID;
        for (int lin = t; lin < 64*HID; lin += 256) xsh[lin] = x1[xbase + lin];
    }
    __syncthreads();
    float accA[4] = {0,0,0,0}, accG[4] = {0,0,0,0}, accX[4] = {0,0,0,0};
    int cA[4], kA[4], cX[4], dX[4];
    #pragma unroll
    for (int q = 0; q < 4; q++){
        int p = t + q*256;
        cA[q] = p >> 5; kA[q] = p & 31;
        cX[q] = p / HID; dX[q] = p - cX[q]*HID;   // valid only when p < 960
    }
    for (int r = 0; r < 64; r++){
        const float* sr = ssh + r*C1;
        const float* tr = tsh + r*C1;
        const float* xr = xsh + r*HID;
        #pragma unroll
        for (int q = 0; q < 4; q++){
            float sc = sr[cA[q]];
            accA[q] += sc*tr[kA[q]];
            accG[q] += sc*sr[kA[q]];
        }
        #pragma unroll
        for (int q = 0; q < 4; q++){
            int p = t + q*256;
            if (p < C1*HID) accX[q] += sr[cX[q]]*xr[dX[q]];
        }
    }
    #pragma unroll
    for (int q = 0; q < 4; q++){
        int p = t + q*256;
        atomicAdd(&adj2[(size_t)b*1024 + p], accA[q]);
        atomicAdd(&Gm[(size_t)b*1024 + p], accG[q]);
        if (p < C1*HID) atomicAdd(&x2[((size_t)b*C1 + cX[q])*HID + dX[q]], accX[q]);
    }
}

// ---------- finalize reg1 ingredients: trace(adj2), ||G||_F^2 ----------
__global__ void k_finalize(const float* __restrict__ adj2, const float* __restrict__ Gm,
                           float* __restrict__ scal){
    int b = blockIdx.x;
    int t = threadIdx.x;   // 256
    float ltr = 0.f, lfr = 0.f;
    for (int p = t; p < 1024; p += 256){
        float g = Gm[(size_t)b*1024 + p];
        lfr += g*g;
        if ((p >> 5) == (p & 31)) ltr += adj2[(size_t)b*1024 + p];
    }
    __shared__ float red[256];
    red[t] = ltr; __syncthreads();
    for (int s = 128; s > 0; s >>= 1){ if (t < s) red[t] += red[t+s]; __syncthreads(); }
    if (t == 0) atomicAdd(&scal[1], red[0]);
    __syncthreads();
    red[t] = lfr; __syncthreads();
    for (int s = 128; s > 0; s >>= 1){ if (t < s) red[t] += red[t+s]; __syncthreads(); }
    if (t == 0) atomicAdd(&scal[2], red[0]);
}

// ---------- fused tail: pool-conv2 prep + agg + diffpool2 (graph-local) ----------
__global__ void k_tail(const float* __restrict__ x2, const float* __restrict__ adj2,
                       const float* __restrict__ Wp2, const float* __restrict__ asp,
                       const float* __restrict__ adp, const float* __restrict__ Wep2,
                       float* __restrict__ x3, float* __restrict__ scal){
    int b = blockIdx.x;
    int t = threadIdx.x;  // 256
    __shared__ float x2s[C1*HID];    // 960
    __shared__ float a2s[C1*C1];     // 1024
    __shared__ float Wps[HID*C2];    // 120
    __shared__ float h2s[C1*C2];
    __shared__ float hs2s[C1], hd2s[C1];
    __shared__ float sss[C1*C2];     // softmax(s2)
    __shared__ float red[256];
    for (int i = t; i < C1*HID; i += 256) x2s[i] = x2[(size_t)b*C1*HID + i];
    for (int i = t; i < C1*C1; i += 256) a2s[i] = adj2[(size_t)b*C1*C1 + i];
    if (t < HID*C2) Wps[t] = Wp2[t];
    __syncthreads();
    // phase 1: h2 = x2@Wp2 + attention scalars (32 threads, one per pooled node)
    if (t < C1){
        float s = 0.f, dd = 0.f;
        #pragma unroll
        for (int c = 0; c < C2; c++){
            float a = 0.f;
            #pragma unroll
            for (int d = 0; d < HID; d++) a += x2s[t*HID + d]*Wps[d*C2 + c];
            h2s[t*C2 + c] = a;
            s += a*asp[c]; dd += a*adp[c];
        }
        hs2s[t] = s; hd2s[t] = dd;
    }
    __syncthreads();
    // phase 2: dense EGAT agg over 32 sources + immediate softmax over C2
    if (t < C1){
        int j = t;
        float hdv = hd2s[j];
        float wep = Wep2[0];
        float m = -INFINITY;
        for (int i = 0; i < C1; i++)
            m = fmaxf(m, lrelu(hs2s[i] + hdv + a2s[i*C1 + j]*wep));
        float den = 0.f;
        float acc[C2] = {0,0,0,0};
        for (int i = 0; i < C1; i++){
            float ex = expf(lrelu(hs2s[i] + hdv + a2s[i*C1 + j]*wep) - m);
            den += ex;
            #pragma unroll
            for (int c = 0; c < C2; c++) acc[c] += ex * h2s[i*C2 + c];
        }
        float inv = 1.f/(den + 1e-16f);
        float v[C2]; float mx = -INFINITY;
        #pragma unroll
        for (int c = 0; c < C2; c++){ v[c] = acc[c]*inv; mx = fmaxf(mx, v[c]); }
        float sum = 0.f;
        #pragma unroll
        for (int c = 0; c < C2; c++){ v[c] = expf(v[c] - mx); sum += v[c]; }
        float i2 = 1.f/sum;
        #pragma unroll
        for (int c = 0; c < C2; c++) sss[j*C2 + c] = v[c]*i2;
    }
    __syncthreads();
    // phase 3: x3 = S^T x2 and reg2
    if (t < C2*HID){
        int c = t / HID, d = t % HID;
        float a = 0.f;
        #pragma unroll
        for (int n = 0; n < C1; n++) a += sss[n*C2 + c]*x2s[n*HID + d];
        x3[(size_t)b*C2*HID + t] = a;
    }
    float loc = 0.f;
    for (int p = t; p < 1024; p += 256){
        int n = p >> 5, mm = p & 31;
        float dot = 0.f;
        #pragma unroll
        for (int c = 0; c < C2; c++) dot += sss[n*C2 + c]*sss[mm*C2 + c];
        float df = a2s[p] - dot;
        loc += df*df;
    }
    red[t] = loc; __syncthreads();
    for (int s = 128; s > 0; s >>= 1){ if (t < s) red[t] += red[t+s]; __syncthreads(); }
    if (t == 0) atomicAdd(&scal[3], red[0]);
}

// ---------- final MLP + reg assembly ----------
__global__ void k_mlp(const float* __restrict__ x3, const float* __restrict__ Wf1,
                      const float* __restrict__ bf1, const float* __restrict__ Wf2,
                      const float* __restrict__ bf2, const float* __restrict__ scal,
                      float* __restrict__ out){
    __shared__ float zsh[NB*32];
    int t = threadIdx.x;   // 512
    if (t < NB*32){
        int b = t >> 5, j = t & 31;
        float a = bf1[j];
        const float* xr = x3 + (size_t)b*C2*HID;
        #pragma unroll 4
        for (int k = 0; k < C2*HID; k++) a += xr[k]*Wf1[k*32 + j];
        zsh[t] = fmaxf(a, 0.f);
    }
    __syncthreads();
    if (t < NB*2){
        int b = t >> 1, o = t & 1;
        float a = bf2[o];
        #pragma unroll
        for (int j = 0; j < 32; j++) a += zsh[b*32 + j]*Wf2[j*2 + o];
        out[t] = a;
    }
    if (t == 0){
        float adjsum = scal[0], tr = scal[1], fr = scal[2], r2 = scal[3];
        float reg1 = (adjsum - 2.f*tr + fr) * (1.f/16777216.f);
        float reg2 = r2 * (1.f/16384.f);
        out[32] = 10.f*reg1 + 0.1f*reg2;
    }
}

extern "C" void kernel_launch(void* const* d_in, const int* in_sizes, int n_in,
                              void* d_out, int out_size, void* d_ws, size_t ws_size,
                              hipStream_t stream) {
    const float* x    = (const float*)d_in[0];
    const int*   ei   = (const int*)d_in[1];
    const float* ea   = (const float*)d_in[2];
    // d_in[3] = y (unused); d_in[4] = adj (algebraically eliminated — never read)
    const float* W1   = (const float*)d_in[5];
    const float* as1  = (const float*)d_in[6];
    const float* ad1  = (const float*)d_in[7];
    const float* We1  = (const float*)d_in[8];
    const float* Wp1  = (const float*)d_in[9];
    const float* asp1 = (const float*)d_in[10];
    const float* adp1 = (const float*)d_in[11];
    const float* Wep1 = (const float*)d_in[12];
    const float* Wp2  = (const float*)d_in[13];
    const float* asp2 = (const float*)d_in[14];
    const float* adp2 = (const float*)d_in[15];
    const float* Wep2 = (const float*)d_in[16];
    const float* Wf1  = (const float*)d_in[17];
    const float* bf1  = (const float*)d_in[18];
    const float* Wf2  = (const float*)d_in[19];
    const float* bf2  = (const float*)d_in[20];
    float* out = (float*)d_out;

    const int* srcA = ei;
    const int* dstA = ei + EE;

    char* wp = (char*)d_ws;
    auto carve = [&](size_t bytes)->char*{
        char* p = wp;
        wp += (bytes + 255) & ~(size_t)255;
        return p;
    };
    float* h1    = (float*)carve((size_t)NN*HID*4);
    float* hs1   = (float*)carve((size_t)NN*NHEADS*4);
    float* hd1   = (float*)carve((size_t)NN*NHEADS*4);
    float* ew1s  = (float*)carve((size_t)EE*NHEADS*4);
    float* ewp1s = (float*)carve((size_t)EE*4);
    float* x1    = (float*)carve((size_t)NN*HID*4);
    float* hp1   = (float*)carve((size_t)NN*C1*4);
    float* hsp   = (float*)carve((size_t)NN*4);
    float* hdp   = (float*)carve((size_t)NN*4);
    float* s1    = (float*)carve((size_t)NN*C1*4);
    float* ssoft = (float*)carve((size_t)NN*C1*4);
    float* T     = (float*)carve((size_t)NN*C1*4);
    // --- zero-init region (contiguous): x2, adj2, Gm ---
    float* x2    = (float*)carve((size_t)NB*C1*HID*4);   // 61440 B (256-aligned)
    float* adj2  = (float*)carve((size_t)NB*C1*C1*4);    // 65536 B
    float* Gm    = (float*)carve((size_t)NB*C1*C1*4);    // 65536 B
    // ---------------------------------------------------
    float* x3    = (float*)carve((size_t)NB*C2*HID*4);
    float* scal  = (float*)carve(16*4);
    // --- zero-init region (contiguous): deg, degS ---
    int* deg     = (int*)carve((size_t)NN*4);
    int* degS    = (int*)carve((size_t)NN*4);
    // ------------------------------------------------
    int* rowptr  = (int*)carve((size_t)(NN+1)*4);
    int* rowptrS = (int*)carve((size_t)(NN+1)*4);
    int* fill    = (int*)carve((size_t)NN*4);
    int* fillS   = (int*)carve((size_t)NN*4);
    int2* se     = (int2*)carve((size_t)EE*8);
    int* nbrS    = (int*)carve((size_t)EE*4);
    int* unbr    = (int*)carve((size_t)EE*4);
    int* ucnt    = (int*)carve((size_t)NN*4);

    hipMemsetAsync(deg, 0, (size_t)2*NN*4, stream);        // deg + degS contiguous
    hipMemsetAsync(scal, 0, 16*4, stream);
    hipMemsetAsync(x2, 0, (size_t)(NB*C1*HID + 2*NB*C1*C1)*4, stream);  // x2+adj2+Gm

    const int TB = 256;
    dim3 gN((NN + TB - 1)/TB), gE(EE/TB);   // gE = 2048 (exact)

    // node projection (independent of graph structure)
    k_node_proj1<<<gN, TB, 0, stream>>>(x, W1, as1, ad1, h1, hs1, hd1);

    // dual CSR build (XCD-affine edge chunks)
    k_hist2<<<gE, TB, 0, stream>>>(srcA, dstA, deg, degS);
    k_scan2f<<<dim3(2), 1024, 0, stream>>>(deg, degS, rowptr, rowptrS, fill, fillS);
    k_scatter2<<<gE, TB, 0, stream>>>(srcA, dstA, fill, fillS, se, nbrS);

    // dedup unique out-neighbors via LDS bitmap + sum(A)
    k_dedup<<<dim3(NN/TB), TB, 0, stream>>>(rowptrS, nbrS, unbr, ucnt, scal);

    // edge projections over CSR slots (coalesced writes, L2 ea gathers)
    k_edge_proj<<<gE, TB, 0, stream>>>(ea, We1, Wep1, se, ew1s, ewp1s);

    // conv1: thread per (node, head), single-pass online softmax
    k_conv1_agg<<<dim3((NN*NHEADS + TB - 1)/TB), TB, 0, stream>>>(se, rowptr, h1, hs1, hd1, ew1s, x1);

    // pool-conv1
    k_node_proj_p1<<<gN, TB, 0, stream>>>(x1, Wp1, asp1, adp1, hp1, hsp, hdp);
    k_pool1_agg<<<dim3((NN*4 + TB - 1)/TB), TB, 0, stream>>>(se, rowptr, hp1, hsp, hdp, ewp1s, s1);

    // diffpool1
    k_soft32<<<gN, TB, 0, stream>>>(s1, ssoft);
    k_T<<<dim3((NN*4 + TB - 1)/TB), TB, 0, stream>>>(rowptrS, unbr, ucnt, ssoft, T);
    k_partials<<<dim3(16, NB), TB, 0, stream>>>(ssoft, T, x1, adj2, Gm, x2);
    k_finalize<<<dim3(NB), TB, 0, stream>>>(adj2, Gm, scal);

    // fused tail: pool-conv2 + diffpool2 + reg2
    k_tail<<<dim3(NB), TB, 0, stream>>>(x2, adj2, Wp2, asp2, adp2, Wep2, x3, scal);

    // MLP + output
    k_mlp<<<1, 512, 0, stream>>>(x3, Wf1, bf1, Wf2, bf2, scal, out);
}

// Round 9
// 403.360 us; speedup vs baseline: 1.1555x; 1.0268x over previous
//
#include <hip/hip_runtime.h>
#include <math.h>

#define NB 16
#define NPG 1024
#define DIN 16
#define ED 8
#define NHEADS 5
#define OUT1 6
#define HID 30
#define C1 32
#define C2 4
#define NN (NB*NPG)      // 16384 nodes
#define EE (NN*32)       // 524288 edges
#define EPG 32768        // edges per graph (graph-contiguous in edge_index)

__device__ __forceinline__ float lrelu(float v){ return v >= 0.f ? v : 0.2f*v; }

// XCD-affinity edge-chunk mapping: all blocks touching graph g land on XCD g%8
// (dispatch round-robins XCDs by blockIdx; performance-only heuristic).
// valid for blockIdx.x < 2048; returns first edge/slot of this block's chunk.
__device__ __forceinline__ size_t xcd_chunk_base(){
    int x = blockIdx.x & 7;
    int j = blockIdx.x >> 3;            // 0..255 position within this XCD
    int g = x + 8*(j >> 7);             // 2 graphs per XCD
    int c = j & 127;                    // 128 chunks per graph
    return (size_t)g*EPG + (size_t)c*256;
}

// ---------- merged: dual histogram (blocks 0..2047) + node projection (2048..2111) ----------
__global__ void k_hist_proj(const int* __restrict__ src, const int* __restrict__ dst,
                            int* __restrict__ deg, int* __restrict__ degS,
                            const float* __restrict__ x, const float* __restrict__ W1,
                            const float* __restrict__ as1, const float* __restrict__ ad1,
                            float* __restrict__ h1, float* __restrict__ hs1, float* __restrict__ hd1){
    __shared__ float Ws[DIN*HID];
    __shared__ float as_s[HID], ad_s[HID];
    if (blockIdx.x < 2048){
        size_t e = xcd_chunk_base() + threadIdx.x;
        atomicAdd(&deg[dst[e]], 1);
        atomicAdd(&degS[src[e]], 1);
        return;
    }
    // node projection part
    for (int i = threadIdx.x; i < DIN*HID; i += blockDim.x) Ws[i] = W1[i];
    if (threadIdx.x < HID){ as_s[threadIdx.x] = as1[threadIdx.x]; ad_s[threadIdx.x] = ad1[threadIdx.x]; }
    __syncthreads();
    int n = (blockIdx.x - 2048)*blockDim.x + threadIdx.x;
    if (n >= NN) return;
    float xv[DIN];
    #pragma unroll
    for (int i = 0; i < DIN; i++) xv[i] = x[n*DIN + i];
    float hv[HID];
    #pragma unroll
    for (int j = 0; j < HID; j++){
        float a = 0.f;
        #pragma unroll
        for (int i = 0; i < DIN; i++) a += xv[i]*Ws[i*HID + j];
        hv[j] = a; h1[(size_t)n*HID + j] = a;
    }
    #pragma unroll
    for (int h = 0; h < NHEADS; h++){
        float s = 0.f, d = 0.f;
        #pragma unroll
        for (int c = 0; c < OUT1; c++){ s += hv[h*OUT1+c]*as_s[h*OUT1+c]; d += hv[h*OUT1+c]*ad_s[h*OUT1+c]; }
        hs1[n*NHEADS + h] = s; hd1[n*NHEADS + h] = d;
    }
}

// ---------- both exclusive scans + fill copies: 2 blocks, wave-shfl scan ----------
__global__ __launch_bounds__(1024) void k_scan2f(const int* __restrict__ deg,
                        const int* __restrict__ degS,
                        int* __restrict__ rowptr, int* __restrict__ rowptrS,
                        int* __restrict__ fill, int* __restrict__ fillS){
    __shared__ int wtot[16];
    __shared__ int wbase[16];
    const int* d = (blockIdx.x == 0) ? deg    : degS;
    int* rp      = (blockIdx.x == 0) ? rowptr : rowptrS;
    int* fl      = (blockIdx.x == 0) ? fill   : fillS;
    int t = threadIdx.x;
    int lane = t & 63, wv = t >> 6;
    int base = t*16;
    int loc[16]; int tot = 0;
    #pragma unroll
    for (int i = 0; i < 16; i++){ loc[i] = tot; tot += d[base + i]; }
    int sincl = tot;                       // wave-inclusive scan of thread totals
    #pragma unroll
    for (int off = 1; off < 64; off <<= 1){
        int v = __shfl_up(sincl, off, 64);
        if (lane >= off) sincl += v;
    }
    if (lane == 63) wtot[wv] = sincl;
    __syncthreads();
    if (t == 0){
        int run = 0;
        #pragma unroll
        for (int w = 0; w < 16; w++){ wbase[w] = run; run += wtot[w]; }
    }
    __syncthreads();
    int gexcl = wbase[wv] + sincl - tot;   // global exclusive prefix for this thread
    #pragma unroll
    for (int i = 0; i < 16; i++){
        int v = gexcl + loc[i];
        rp[base + i] = v;
        fl[base + i] = v;
    }
    if (t == 1023) rp[NN] = gexcl + tot;
}

// dst-CSR: se[slot] = (src[e], e)   (for aggregations + edge projection)
// src-CSR: nbrS[slot] = dst[e]      (for dedup / T = A*S)
__global__ void k_scatter2(const int* __restrict__ src, const int* __restrict__ dst,
                           int* __restrict__ fill, int* __restrict__ fillS,
                           int2* __restrict__ se, int* __restrict__ nbrS){
    size_t e = xcd_chunk_base() + threadIdx.x;
    int s = src[e], d = dst[e];
    int p = atomicAdd(&fill[d], 1);
    se[p] = make_int2(s, (int)e);
    int pS = atomicAdd(&fillS[s], 1);
    nbrS[pS] = d;
}

// ---------- merged: edge projections (blocks 0..2047) + dedup (2048..2111) ----------
__global__ void k_proj_dedup(const float* __restrict__ ea, const float* __restrict__ We1,
                             const float* __restrict__ Wep1, const int2* __restrict__ se,
                             float* __restrict__ ew1s, float* __restrict__ ewp1s,
                             const int* __restrict__ rowptrS, const int* __restrict__ nbrS,
                             int* __restrict__ unbr, int* __restrict__ ucnt,
                             float* __restrict__ scal){
    __shared__ unsigned int bm[256*33];   // dedup bitmap (33-word stride)
    __shared__ int red[256];
    __shared__ float W[ED*NHEADS];
    __shared__ float Wp[ED];
    int t = threadIdx.x;
    if (blockIdx.x < 2048){
        // edge-attr projections over CSR slots: coalesced writes, L2 ea gathers
        if (t < ED*NHEADS) W[t] = We1[t];
        if (t < ED) Wp[t] = Wep1[t];
        __syncthreads();
        size_t k = xcd_chunk_base() + t;
        int e = se[k].y;
        float a[ED];
        #pragma unroll
        for (int i = 0; i < ED; i++) a[i] = ea[(size_t)e*ED + i];
        #pragma unroll
        for (int h = 0; h < NHEADS; h++){
            float s = 0.f;
            #pragma unroll
            for (int i = 0; i < ED; i++) s += a[i]*W[i*NHEADS + h];
            ew1s[k*NHEADS + h] = s;
        }
        float s = 0.f;
        #pragma unroll
        for (int i = 0; i < ED; i++) s += a[i]*Wp[i];
        ewp1s[k] = s;
        return;
    }
    // dedup via per-thread LDS bitmap (neighbors are block-local 0..1023)
    unsigned int* mybm = &bm[t*33];
    #pragma unroll
    for (int i = 0; i < 32; i++) mybm[i] = 0u;
    int n = (blockIdx.x - 2048)*blockDim.x + t;
    int cnt = 0;
    if (n < NN){
        int k0 = rowptrS[n], k1 = rowptrS[n+1];
        for (int k = k0; k < k1; k++){
            int m = nbrS[k];
            int loc = m & (NPG-1);
            unsigned int w = (unsigned int)(loc >> 5);
            unsigned int bit = 1u << (loc & 31);
            unsigned int old = mybm[w];
            if (!(old & bit)){
                mybm[w] = old | bit;
                unbr[k0 + cnt] = m;
                cnt++;
            }
        }
        ucnt[n] = cnt;
    }
    red[t] = cnt; __syncthreads();
    for (int s = 128; s > 0; s >>= 1){ if (t < s) red[t] += red[t+s]; __syncthreads(); }
    if (t == 0) atomicAdd(&scal[0], (float)red[0]);
}

// ---------- conv1 aggregation: online softmax, thread per (node, head, 3-ch half) ----------
__global__ void k_conv1_agg(const int2* __restrict__ se, const int* __restrict__ rowptr,
                            const float* __restrict__ h1,
                            const float* __restrict__ hs1, const float* __restrict__ hd1,
                            const float* __restrict__ ew1s, float* __restrict__ x1){
    int tid = blockIdx.x*blockDim.x + threadIdx.x;
    if (tid >= NN*NHEADS*2) return;
    int n = tid / (NHEADS*2);
    int r = tid - n*(NHEADS*2);
    int h = r >> 1;
    int q = r & 1;               // 3-channel half
    int k0 = rowptr[n], k1 = rowptr[n+1];
    float hdv = hd1[n*NHEADS + h];
    float m = -INFINITY, den = 0.f;
    float acc[3] = {0.f, 0.f, 0.f};
    for (int k = k0; k < k1; k++){
        int s = se[k].x;
        float l = lrelu(hs1[s*NHEADS + h] + hdv + ew1s[(size_t)k*NHEADS + h]);
        float mn = fmaxf(m, l);
        float f  = expf(m - mn);     // first iter: exp(-inf)=0
        float ex = expf(l - mn);
        m = mn;
        den = den*f + ex;
        const float* hr = h1 + (size_t)s*HID + h*OUT1 + q*3;
        #pragma unroll
        for (int c = 0; c < 3; c++) acc[c] = acc[c]*f + ex*hr[c];
    }
    float inv = 1.f / (den + 1e-16f);
    #pragma unroll
    for (int c = 0; c < 3; c++) x1[(size_t)n*HID + h*OUT1 + q*3 + c] = acc[c]*inv;
}

// ---------- pool-conv1 prep: hp1 = x1@Wp1 (30x32); scalars ----------
__global__ void k_node_proj_p1(const float* __restrict__ x1, const float* __restrict__ Wp1,
                               const float* __restrict__ asp, const float* __restrict__ adp,
                               float* __restrict__ hp1, float* __restrict__ hsp, float* __restrict__ hdp){
    __shared__ float Ws[HID*C1];
    __shared__ float as_s[C1], ad_s[C1];
    for (int i = threadIdx.x; i < HID*C1; i += blockDim.x) Ws[i] = Wp1[i];
    if (threadIdx.x < C1){ as_s[threadIdx.x] = asp[threadIdx.x]; ad_s[threadIdx.x] = adp[threadIdx.x]; }
    __syncthreads();
    int n = blockIdx.x*blockDim.x + threadIdx.x;
    if (n >= NN) return;
    float xv[HID];
    #pragma unroll
    for (int d = 0; d < HID; d++) xv[d] = x1[(size_t)n*HID + d];
    float s = 0.f, dd = 0.f;
    for (int c = 0; c < C1; c++){
        float a = 0.f;
        #pragma unroll
        for (int d = 0; d < HID; d++) a += xv[d]*Ws[d*C1 + c];
        hp1[(size_t)n*C1 + c] = a;
        s += a*as_s[c]; dd += a*ad_s[c];
    }
    hsp[n] = s; hdp[n] = dd;
}

// ---------- pool-conv1 aggregation: online softmax, thread per (node, 4-ch eighth) ----------
__global__ void k_pool1_agg(const int2* __restrict__ se, const int* __restrict__ rowptr,
                            const float* __restrict__ hp1,
                            const float* __restrict__ hsp, const float* __restrict__ hdp,
                            const float* __restrict__ ewp1s, float* __restrict__ s1){
    int tid = blockIdx.x*blockDim.x + threadIdx.x;
    if (tid >= NN*8) return;
    int q = tid & 7;
    int n = tid >> 3;
    int k0 = rowptr[n], k1 = rowptr[n+1];
    float hdv = hdp[n];
    float m = -INFINITY, den = 0.f;
    float acc[4] = {0.f, 0.f, 0.f, 0.f};
    for (int k = k0; k < k1; k++){
        int s = se[k].x;
        float l = lrelu(hsp[s] + hdv + ewp1s[k]);
        float mn = fmaxf(m, l);
        float f  = expf(m - mn);
        float ex = expf(l - mn);
        m = mn;
        den = den*f + ex;
        const float* hr = hp1 + (size_t)s*C1 + q*4;
        #pragma unroll
        for (int c = 0; c < 4; c++) acc[c] = acc[c]*f + ex*hr[c];
    }
    float inv = 1.f / (den + 1e-16f);
    #pragma unroll
    for (int c = 0; c < 4; c++) s1[(size_t)n*C1 + q*4 + c] = acc[c]*inv;
}

// ---------- cluster softmax (over 32) ----------
__global__ void k_soft32(const float* __restrict__ s1, float* __restrict__ ssoft){
    int n = blockIdx.x*blockDim.x + threadIdx.x;
    if (n >= NN) return;
    float v[C1];
    float m = -INFINITY;
    #pragma unroll
    for (int c = 0; c < C1; c++){ v[c] = s1[(size_t)n*C1 + c]; m = fmaxf(m, v[c]); }
    float sum = 0.f;
    #pragma unroll
    for (int c = 0; c < C1; c++){ v[c] = expf(v[c] - m); sum += v[c]; }
    float inv = 1.f/sum;
    #pragma unroll
    for (int c = 0; c < C1; c++) ssoft[(size_t)n*C1 + c] = v[c]*inv;
}

// ---------- T[n,:] = sum over unique out-neighbors m of S[m,:] (thread per (node, eighth)) ----------
__global__ void k_T(const int* __restrict__ rowptrS, const int* __restrict__ unbr,
                    const int* __restrict__ ucnt, const float* __restrict__ ssoft,
                    float* __restrict__ T){
    int tid = blockIdx.x*blockDim.x + threadIdx.x;
    if (tid >= NN*8) return;
    int q = tid & 7;
    int n = tid >> 3;
    int k0 = rowptrS[n];
    int cnt = ucnt[n];
    float acc[4] = {0.f, 0.f, 0.f, 0.f};
    for (int i = 0; i < cnt; i++){
        int m = unbr[k0 + i];
        const float* sr = ssoft + (size_t)m*C1 + q*4;
        #pragma unroll
        for (int c = 0; c < 4; c++) acc[c] += sr[c];
    }
    #pragma unroll
    for (int c = 0; c < 4; c++) T[(size_t)n*C1 + q*4 + c] = acc[c];
}

// ---------- fused partials over 64-node chunks:
//   adj2 += S_chunk^T T_chunk ; G += S_chunk^T S_chunk ; x2 += S_chunk^T X_chunk
__global__ void k_partials(const float* __restrict__ ssoft, const float* __restrict__ T,
                           const float* __restrict__ x1,
                           float* __restrict__ adj2, float* __restrict__ Gm,
                           float* __restrict__ x2){
    int b  = blockIdx.y;
    int n0 = blockIdx.x * 64;
    int t  = threadIdx.x;   // 256
    __shared__ float ssh[64*C1];
    __shared__ float tsh[64*C1];
    __shared__ float xsh[64*HID];
    {
        size_t sbase = ((size_t)b*NPG + n0)*C1;
        #pragma unroll
        for (int i = 0; i < 8; i++){
            int lin = t + i*256;
            ssh[lin] = ssoft[sbase + lin];
            tsh[lin] = T[sbase + lin];
        }
        size_t xbase = ((size_t)b*NPG + n0)*HID;
        for (int lin = t; lin < 64*HID; lin += 256) xsh[lin] = x1[xbase + lin];
    }
    __syncthreads();
    float accA[4] = {0,0,0,0}, accG[4] = {0,0,0,0}, accX[4] = {0,0,0,0};
    int cA[4], kA[4], cX[4], dX[4];
    #pragma unroll
    for (int q = 0; q < 4; q++){
        int p = t + q*256;
        cA[q] = p >> 5; kA[q] = p & 31;
        cX[q] = p / HID; dX[q] = p - cX[q]*HID;   // valid only when p < 960
    }
    for (int r = 0; r < 64; r++){
        const float* sr = ssh + r*C1;
        const float* tr = tsh + r*C1;
        const float* xr = xsh + r*HID;
        #pragma unroll
        for (int q = 0; q < 4; q++){
            float sc = sr[cA[q]];
            accA[q] += sc*tr[kA[q]];
            accG[q] += sc*sr[kA[q]];
        }
        #pragma unroll
        for (int q = 0; q < 4; q++){
            int p = t + q*256;
            if (p < C1*HID) accX[q] += sr[cX[q]]*xr[dX[q]];
        }
    }
    #pragma unroll
    for (int q = 0; q < 4; q++){
        int p = t + q*256;
        atomicAdd(&adj2[(size_t)b*1024 + p], accA[q]);
        atomicAdd(&Gm[(size_t)b*1024 + p], accG[q]);
        if (p < C1*HID) atomicAdd(&x2[((size_t)b*C1 + cX[q])*HID + dX[q]], accX[q]);
    }
}

// ---------- finalize reg1 ingredients: trace(adj2), ||G||_F^2 ----------
__global__ void k_finalize(const float* __restrict__ adj2, const float* __restrict__ Gm,
                           float* __restrict__ scal){
    int b = blockIdx.x;
    int t = threadIdx.x;   // 256
    float ltr = 0.f, lfr = 0.f;
    for (int p = t; p < 1024; p += 256){
        float g = Gm[(size_t)b*1024 + p];
        lfr += g*g;
        if ((p >> 5) == (p & 31)) ltr += adj2[(size_t)b*1024 + p];
    }
    __shared__ float red[256];
    red[t] = ltr; __syncthreads();
    for (int s = 128; s > 0; s >>= 1){ if (t < s) red[t] += red[t+s]; __syncthreads(); }
    if (t == 0) atomicAdd(&scal[1], red[0]);
    __syncthreads();
    red[t] = lfr; __syncthreads();
    for (int s = 128; s > 0; s >>= 1){ if (t < s) red[t] += red[t+s]; __syncthreads(); }
    if (t == 0) atomicAdd(&scal[2], red[0]);
}

// ---------- fused tail: pool-conv2 prep + agg + diffpool2 (graph-local) ----------
__global__ void k_tail(const float* __restrict__ x2, const float* __restrict__ adj2,
                       const float* __restrict__ Wp2, const float* __restrict__ asp,
                       const float* __restrict__ adp, const float* __restrict__ Wep2,
                       float* __restrict__ x3, float* __restrict__ scal){
    int b = blockIdx.x;
    int t = threadIdx.x;  // 256
    __shared__ float x2s[C1*HID];    // 960
    __shared__ float a2s[C1*C1];     // 1024
    __shared__ float Wps[HID*C2];    // 120
    __shared__ float h2s[C1*C2];
    __shared__ float hs2s[C1], hd2s[C1];
    __shared__ float sss[C1*C2];     // softmax(s2)
    __shared__ float red[256];
    for (int i = t; i < C1*HID; i += 256) x2s[i] = x2[(size_t)b*C1*HID + i];
    for (int i = t; i < C1*C1; i += 256) a2s[i] = adj2[(size_t)b*C1*C1 + i];
    if (t < HID*C2) Wps[t] = Wp2[t];
    __syncthreads();
    // phase 1: h2 = x2@Wp2 + attention scalars (32 threads, one per pooled node)
    if (t < C1){
        float s = 0.f, dd = 0.f;
        #pragma unroll
        for (int c = 0; c < C2; c++){
            float a = 0.f;
            #pragma unroll
            for (int d = 0; d < HID; d++) a += x2s[t*HID + d]*Wps[d*C2 + c];
            h2s[t*C2 + c] = a;
            s += a*asp[c]; dd += a*adp[c];
        }
        hs2s[t] = s; hd2s[t] = dd;
    }
    __syncthreads();
    // phase 2: dense EGAT agg over 32 sources + immediate softmax over C2
    if (t < C1){
        int j = t;
        float hdv = hd2s[j];
        float wep = Wep2[0];
        float m = -INFINITY;
        for (int i = 0; i < C1; i++)
            m = fmaxf(m, lrelu(hs2s[i] + hdv + a2s[i*C1 + j]*wep));
        float den = 0.f;
        float acc[C2] = {0,0,0,0};
        for (int i = 0; i < C1; i++){
            float ex = expf(lrelu(hs2s[i] + hdv + a2s[i*C1 + j]*wep) - m);
            den += ex;
            #pragma unroll
            for (int c = 0; c < C2; c++) acc[c] += ex * h2s[i*C2 + c];
        }
        float inv = 1.f/(den + 1e-16f);
        float v[C2]; float mx = -INFINITY;
        #pragma unroll
        for (int c = 0; c < C2; c++){ v[c] = acc[c]*inv; mx = fmaxf(mx, v[c]); }
        float sum = 0.f;
        #pragma unroll
        for (int c = 0; c < C2; c++){ v[c] = expf(v[c] - mx); sum += v[c]; }
        float i2 = 1.f/sum;
        #pragma unroll
        for (int c = 0; c < C2; c++) sss[j*C2 + c] = v[c]*i2;
    }
    __syncthreads();
    // phase 3: x3 = S^T x2 and reg2
    if (t < C2*HID){
        int c = t / HID, d = t % HID;
        float a = 0.f;
        #pragma unroll
        for (int n = 0; n < C1; n++) a += sss[n*C2 + c]*x2s[n*HID + d];
        x3[(size_t)b*C2*HID + t] = a;
    }
    float loc = 0.f;
    for (int p = t; p < 1024; p += 256){
        int n = p >> 5, mm = p & 31;
        float dot = 0.f;
        #pragma unroll
        for (int c = 0; c < C2; c++) dot += sss[n*C2 + c]*sss[mm*C2 + c];
        float df = a2s[p] - dot;
        loc += df*df;
    }
    red[t] = loc; __syncthreads();
    for (int s = 128; s > 0; s >>= 1){ if (t < s) red[t] += red[t+s]; __syncthreads(); }
    if (t == 0) atomicAdd(&scal[3], red[0]);
}

// ---------- final MLP + reg assembly ----------
__global__ void k_mlp(const float* __restrict__ x3, const float* __restrict__ Wf1,
                      const float* __restrict__ bf1, const float* __restrict__ Wf2,
                      const float* __restrict__ bf2, const float* __restrict__ scal,
                      float* __restrict__ out){
    __shared__ float zsh[NB*32];
    int t = threadIdx.x;   // 512
    if (t < NB*32){
        int b = t >> 5, j = t & 31;
        float a = bf1[j];
        const float* xr = x3 + (size_t)b*C2*HID;
        #pragma unroll 4
        for (int k = 0; k < C2*HID; k++) a += xr[k]*Wf1[k*32 + j];
        zsh[t] = fmaxf(a, 0.f);
    }
    __syncthreads();
    if (t < NB*2){
        int b = t >> 1, o = t & 1;
        float a = bf2[o];
        #pragma unroll
        for (int j = 0; j < 32; j++) a += zsh[b*32 + j]*Wf2[j*2 + o];
        out[t] = a;
    }
    if (t == 0){
        float adjsum = scal[0], tr = scal[1], fr = scal[2], r2 = scal[3];
        float reg1 = (adjsum - 2.f*tr + fr) * (1.f/16777216.f);
        float reg2 = r2 * (1.f/16384.f);
        out[32] = 10.f*reg1 + 0.1f*reg2;
    }
}

extern "C" void kernel_launch(void* const* d_in, const int* in_sizes, int n_in,
                              void* d_out, int out_size, void* d_ws, size_t ws_size,
                              hipStream_t stream) {
    const float* x    = (const float*)d_in[0];
    const int*   ei   = (const int*)d_in[1];
    const float* ea   = (const float*)d_in[2];
    // d_in[3] = y (unused); d_in[4] = adj (algebraically eliminated — never read)
    const float* W1   = (const float*)d_in[5];
    const float* as1  = (const float*)d_in[6];
    const float* ad1  = (const float*)d_in[7];
    const float* We1  = (const float*)d_in[8];
    const float* Wp1  = (const float*)d_in[9];
    const float* asp1 = (const float*)d_in[10];
    const float* adp1 = (const float*)d_in[11];
    const float* Wep1 = (const float*)d_in[12];
    const float* Wp2  = (const float*)d_in[13];
    const float* asp2 = (const float*)d_in[14];
    const float* adp2 = (const float*)d_in[15];
    const float* Wep2 = (const float*)d_in[16];
    const float* Wf1  = (const float*)d_in[17];
    const float* bf1  = (const float*)d_in[18];
    const float* Wf2  = (const float*)d_in[19];
    const float* bf2  = (const float*)d_in[20];
    float* out = (float*)d_out;

    const int* srcA = ei;
    const int* dstA = ei + EE;

    char* wp = (char*)d_ws;
    auto carve = [&](size_t bytes)->char*{
        char* p = wp;
        wp += (bytes + 255) & ~(size_t)255;
        return p;
    };
    float* h1    = (float*)carve((size_t)NN*HID*4);
    float* hs1   = (float*)carve((size_t)NN*NHEADS*4);
    float* hd1   = (float*)carve((size_t)NN*NHEADS*4);
    float* ew1s  = (float*)carve((size_t)EE*NHEADS*4);
    float* ewp1s = (float*)carve((size_t)EE*4);
    float* x1    = (float*)carve((size_t)NN*HID*4);
    float* hp1   = (float*)carve((size_t)NN*C1*4);
    float* hsp   = (float*)carve((size_t)NN*4);
    float* hdp   = (float*)carve((size_t)NN*4);
    float* s1    = (float*)carve((size_t)NN*C1*4);
    float* ssoft = (float*)carve((size_t)NN*C1*4);
    float* T     = (float*)carve((size_t)NN*C1*4);
    // --- zero-init region (contiguous): x2, adj2, Gm ---
    float* x2    = (float*)carve((size_t)NB*C1*HID*4);   // 61440 B (256-aligned)
    float* adj2  = (float*)carve((size_t)NB*C1*C1*4);    // 65536 B
    float* Gm    = (float*)carve((size_t)NB*C1*C1*4);    // 65536 B
    // ---------------------------------------------------
    float* x3    = (float*)carve((size_t)NB*C2*HID*4);
    float* scal  = (float*)carve(16*4);
    // --- zero-init region (contiguous): deg, degS ---
    int* deg     = (int*)carve((size_t)NN*4);
    int* degS    = (int*)carve((size_t)NN*4);
    // ------------------------------------------------
    int* rowptr  = (int*)carve((size_t)(NN+1)*4);
    int* rowptrS = (int*)carve((size_t)(NN+1)*4);
    int* fill    = (int*)carve((size_t)NN*4);
    int* fillS   = (int*)carve((size_t)NN*4);
    int2* se     = (int2*)carve((size_t)EE*8);
    int* nbrS    = (int*)carve((size_t)EE*4);
    int* unbr    = (int*)carve((size_t)EE*4);
    int* ucnt    = (int*)carve((size_t)NN*4);

    hipMemsetAsync(deg, 0, (size_t)2*NN*4, stream);        // deg + degS contiguous
    hipMemsetAsync(scal, 0, 16*4, stream);
    hipMemsetAsync(x2, 0, (size_t)(NB*C1*HID + 2*NB*C1*C1)*4, stream);  // x2+adj2+Gm

    const int TB = 256;
    dim3 gN((NN + TB - 1)/TB);

    // merged: dual histogram (2048 blocks) + node projection (64 blocks)
    k_hist_proj<<<dim3(2048 + 64), TB, 0, stream>>>(srcA, dstA, deg, degS,
                                                    x, W1, as1, ad1, h1, hs1, hd1);
    k_scan2f<<<dim3(2), 1024, 0, stream>>>(deg, degS, rowptr, rowptrS, fill, fillS);
    k_scatter2<<<dim3(2048), TB, 0, stream>>>(srcA, dstA, fill, fillS, se, nbrS);

    // merged: edge projections (2048 blocks) + dedup (64 blocks)
    k_proj_dedup<<<dim3(2048 + 64), TB, 0, stream>>>(ea, We1, Wep1, se, ew1s, ewp1s,
                                                     rowptrS, nbrS, unbr, ucnt, scal);

    // conv1: thread per (node, head, 3-ch half), single-pass online softmax
    k_conv1_agg<<<dim3(NN*NHEADS*2/TB), TB, 0, stream>>>(se, rowptr, h1, hs1, hd1, ew1s, x1);

    // pool-conv1
    k_node_proj_p1<<<gN, TB, 0, stream>>>(x1, Wp1, asp1, adp1, hp1, hsp, hdp);
    k_pool1_agg<<<dim3(NN*8/TB), TB, 0, stream>>>(se, rowptr, hp1, hsp, hdp, ewp1s, s1);

    // diffpool1
    k_soft32<<<gN, TB, 0, stream>>>(s1, ssoft);
    k_T<<<dim3(NN*8/TB), TB, 0, stream>>>(rowptrS, unbr, ucnt, ssoft, T);
    k_partials<<<dim3(16, NB), TB, 0, stream>>>(ssoft, T, x1, adj2, Gm, x2);
    k_finalize<<<dim3(NB), TB, 0, stream>>>(adj2, Gm, scal);

    // fused tail: pool-conv2 + diffpool2 + reg2
    k_tail<<<dim3(NB), TB, 0, stream>>>(x2, adj2, Wp2, asp2, adp2, Wep2, x3, scal);

    // MLP + output
    k_mlp<<<1, 512, 0, stream>>>(x3, Wf1, bf1, Wf2, bf2, scal, out);
}

// Round 10
// 332.096 us; speedup vs baseline: 1.4035x; 1.2146x over previous
//
#include <hip/hip_runtime.h>
#include <math.h>

#define NB 16
#define NPG 1024
#define DIN 16
#define ED 8
#define NHEADS 5
#define OUT1 6
#define HID 30
#define C1 32
#define C2 4
#define NN (NB*NPG)      // 16384 nodes
#define EE (NN*32)       // 524288 edges
#define EPG 32768        // edges per graph (graph-contiguous in edge_index)
#define CH 16            // chunks per graph
#define CE 2048          // edges per chunk

__device__ __forceinline__ float lrelu(float v){ return v >= 0.f ? v : 0.2f*v; }

// chunk mapping for 256-block edge kernels: XCD-affine, block -> (g, c)
__device__ __forceinline__ void chunk_gc(int& g, int& c){
    int x = blockIdx.x & 7;
    int j = blockIdx.x >> 3;     // 0..31
    g = x + 8*(j >> 4);          // 2 graphs per XCD
    c = j & 15;
}

// XCD-affinity mapping for 2048-block edge kernels (edge projections)
__device__ __forceinline__ size_t xcd_chunk_base(){
    int x = blockIdx.x & 7;
    int j = blockIdx.x >> 3;            // 0..255 position within this XCD
    int g = x + 8*(j >> 7);             // 2 graphs per XCD
    int c = j & 127;                    // 128 chunks per graph
    return (size_t)g*EPG + (size_t)c*256;
}

// ---------- merged: per-chunk dual LDS histograms (blocks 0..255) + node projection ----------
__global__ void k_hist_chunk(const int* __restrict__ src, const int* __restrict__ dst,
                             int* __restrict__ histD, int* __restrict__ histS,
                             const float* __restrict__ x, const float* __restrict__ W1,
                             const float* __restrict__ as1, const float* __restrict__ ad1,
                             float* __restrict__ h1, float* __restrict__ hs1, float* __restrict__ hd1){
    int t = threadIdx.x;
    if (blockIdx.x < 256){
        __shared__ int hD[NPG], hS[NPG];
        for (int i = t; i < NPG; i += 256){ hD[i] = 0; hS[i] = 0; }
        __syncthreads();
        int g, c; chunk_gc(g, c);
        size_t e0 = ((size_t)g*CH + c)*CE;
        #pragma unroll
        for (int i = 0; i < 8; i++){
            size_t e = e0 + i*256 + t;
            atomicAdd(&hD[dst[e] & (NPG-1)], 1);
            atomicAdd(&hS[src[e] & (NPG-1)], 1);
        }
        __syncthreads();
        size_t hb = ((size_t)g*CH + c)*NPG;
        for (int i = t; i < NPG; i += 256){
            histD[hb + i] = hD[i];
            histS[hb + i] = hS[i];
        }
        return;
    }
    // node projection part (blocks 256..319)
    __shared__ float Ws[DIN*HID];
    __shared__ float as_s[HID], ad_s[HID];
    for (int i = t; i < DIN*HID; i += blockDim.x) Ws[i] = W1[i];
    if (t < HID){ as_s[t] = as1[t]; ad_s[t] = ad1[t]; }
    __syncthreads();
    int n = (blockIdx.x - 256)*blockDim.x + t;
    if (n >= NN) return;
    float xv[DIN];
    #pragma unroll
    for (int i = 0; i < DIN; i++) xv[i] = x[n*DIN + i];
    float hv[HID];
    #pragma unroll
    for (int j = 0; j < HID; j++){
        float a = 0.f;
        #pragma unroll
        for (int i = 0; i < DIN; i++) a += xv[i]*Ws[i*HID + j];
        hv[j] = a; h1[(size_t)n*HID + j] = a;
    }
    #pragma unroll
    for (int h = 0; h < NHEADS; h++){
        float s = 0.f, d = 0.f;
        #pragma unroll
        for (int c2 = 0; c2 < OUT1; c2++){ s += hv[h*OUT1+c2]*as_s[h*OUT1+c2]; d += hv[h*OUT1+c2]*ad_s[h*OUT1+c2]; }
        hs1[n*NHEADS + h] = s; hd1[n*NHEADS + h] = d;
    }
}

// ---------- per-(g,n) exclusive scan over chunks, in place; emits deg ----------
// grid 128 blocks x 256: tids 0..NN-1 -> histD/deg, NN..2NN-1 -> histS/degS.
// n is the fast axis of hist rows -> all accesses coalesced.
__global__ void k_cumhist(int* __restrict__ histD, int* __restrict__ histS,
                          int* __restrict__ deg, int* __restrict__ degS){
    int tid = blockIdx.x*blockDim.x + threadIdx.x;
    int* hist; int* dg;
    if (tid < NN){ hist = histD; dg = deg; }
    else         { hist = histS; dg = degS; tid -= NN; }
    int g = tid >> 10, n = tid & (NPG-1);
    int run = 0;
    #pragma unroll
    for (int c = 0; c < CH; c++){
        size_t idx = ((size_t)g*CH + c)*NPG + n;
        int v = hist[idx];
        hist[idx] = run;
        run += v;
    }
    dg[tid] = run;
}

// ---------- both exclusive scans: 2 blocks, wave-shfl scan ----------
__global__ __launch_bounds__(1024) void k_scan2f(const int* __restrict__ deg,
                        const int* __restrict__ degS,
                        int* __restrict__ rowptr, int* __restrict__ rowptrS){
    __shared__ int wtot[16];
    __shared__ int wbase[16];
    const int* d = (blockIdx.x == 0) ? deg    : degS;
    int* rp      = (blockIdx.x == 0) ? rowptr : rowptrS;
    int t = threadIdx.x;
    int lane = t & 63, wv = t >> 6;
    int base = t*16;
    int loc[16]; int tot = 0;
    #pragma unroll
    for (int i = 0; i < 16; i++){ loc[i] = tot; tot += d[base + i]; }
    int sincl = tot;                       // wave-inclusive scan of thread totals
    #pragma unroll
    for (int off = 1; off < 64; off <<= 1){
        int v = __shfl_up(sincl, off, 64);
        if (lane >= off) sincl += v;
    }
    if (lane == 63) wtot[wv] = sincl;
    __syncthreads();
    if (t == 0){
        int run = 0;
        #pragma unroll
        for (int w = 0; w < 16; w++){ wbase[w] = run; run += wtot[w]; }
    }
    __syncthreads();
    int gexcl = wbase[wv] + sincl - tot;   // global exclusive prefix for this thread
    #pragma unroll
    for (int i = 0; i < 16; i++) rp[base + i] = gexcl + loc[i];
    if (t == 1023) rp[NN] = gexcl + tot;
}

// ---------- deterministic scatter: slot = rowptr + chunk-base + LDS rank (no global atomics) ----------
// dst-CSR: se[slot] = (src[e], e) ; src-CSR: nbrS[slot] = dst[e]
__global__ void k_scatter_det(const int* __restrict__ src, const int* __restrict__ dst,
                              const int* __restrict__ rowptr, const int* __restrict__ rowptrS,
                              const int* __restrict__ histD, const int* __restrict__ histS,
                              int2* __restrict__ se, int* __restrict__ nbrS){
    __shared__ int baseD[NPG], baseS[NPG];
    int t = threadIdx.x;
    int g, c; chunk_gc(g, c);
    size_t hb = ((size_t)g*CH + c)*NPG;
    for (int i = t; i < NPG; i += 256){
        baseD[i] = rowptr[g*NPG + i] + histD[hb + i];
        baseS[i] = rowptrS[g*NPG + i] + histS[hb + i];
    }
    __syncthreads();
    size_t e0 = ((size_t)g*CH + c)*CE;
    #pragma unroll
    for (int i = 0; i < 8; i++){
        size_t e = e0 + i*256 + t;
        int s = src[e], d = dst[e];
        int p = atomicAdd(&baseD[d & (NPG-1)], 1);
        se[p] = make_int2(s, (int)e);
        int pS = atomicAdd(&baseS[s & (NPG-1)], 1);
        nbrS[pS] = d;
    }
}

// ---------- merged: edge projections (blocks 0..2047) + dedup (2048..2111) ----------
__global__ void k_proj_dedup(const float* __restrict__ ea, const float* __restrict__ We1,
                             const float* __restrict__ Wep1, const int2* __restrict__ se,
                             float* __restrict__ ew1s, float* __restrict__ ewp1s,
                             const int* __restrict__ rowptrS, const int* __restrict__ nbrS,
                             int* __restrict__ unbr, int* __restrict__ ucnt,
                             float* __restrict__ scal){
    __shared__ unsigned int bm[256*33];   // dedup bitmap (33-word stride)
    __shared__ int red[256];
    __shared__ float W[ED*NHEADS];
    __shared__ float Wp[ED];
    int t = threadIdx.x;
    if (blockIdx.x < 2048){
        // edge-attr projections over CSR slots: coalesced writes, L2 ea gathers
        if (t < ED*NHEADS) W[t] = We1[t];
        if (t < ED) Wp[t] = Wep1[t];
        __syncthreads();
        size_t k = xcd_chunk_base() + t;
        int e = se[k].y;
        float a[ED];
        #pragma unroll
        for (int i = 0; i < ED; i++) a[i] = ea[(size_t)e*ED + i];
        #pragma unroll
        for (int h = 0; h < NHEADS; h++){
            float s = 0.f;
            #pragma unroll
            for (int i = 0; i < ED; i++) s += a[i]*W[i*NHEADS + h];
            ew1s[k*NHEADS + h] = s;
        }
        float s = 0.f;
        #pragma unroll
        for (int i = 0; i < ED; i++) s += a[i]*Wp[i];
        ewp1s[k] = s;
        return;
    }
    // dedup via per-thread LDS bitmap (neighbors are block-local 0..1023)
    unsigned int* mybm = &bm[t*33];
    #pragma unroll
    for (int i = 0; i < 32; i++) mybm[i] = 0u;
    int n = (blockIdx.x - 2048)*blockDim.x + t;
    int cnt = 0;
    if (n < NN){
        int k0 = rowptrS[n], k1 = rowptrS[n+1];
        for (int k = k0; k < k1; k++){
            int m = nbrS[k];
            int loc = m & (NPG-1);
            unsigned int w = (unsigned int)(loc >> 5);
            unsigned int bit = 1u << (loc & 31);
            unsigned int old = mybm[w];
            if (!(old & bit)){
                mybm[w] = old | bit;
                unbr[k0 + cnt] = m;
                cnt++;
            }
        }
        ucnt[n] = cnt;
    }
    red[t] = cnt; __syncthreads();
    for (int s = 128; s > 0; s >>= 1){ if (t < s) red[t] += red[t+s]; __syncthreads(); }
    if (t == 0) atomicAdd(&scal[0], (float)red[0]);
}

// ---------- conv1 aggregation: online softmax, thread per (node, head, 3-ch half) ----------
__global__ void k_conv1_agg(const int2* __restrict__ se, const int* __restrict__ rowptr,
                            const float* __restrict__ h1,
                            const float* __restrict__ hs1, const float* __restrict__ hd1,
                            const float* __restrict__ ew1s, float* __restrict__ x1){
    int tid = blockIdx.x*blockDim.x + threadIdx.x;
    if (tid >= NN*NHEADS*2) return;
    int n = tid / (NHEADS*2);
    int r = tid - n*(NHEADS*2);
    int h = r >> 1;
    int q = r & 1;               // 3-channel half
    int k0 = rowptr[n], k1 = rowptr[n+1];
    float hdv = hd1[n*NHEADS + h];
    float m = -INFINITY, den = 0.f;
    float acc[3] = {0.f, 0.f, 0.f};
    for (int k = k0; k < k1; k++){
        int s = se[k].x;
        float l = lrelu(hs1[s*NHEADS + h] + hdv + ew1s[(size_t)k*NHEADS + h]);
        float mn = fmaxf(m, l);
        float f  = expf(m - mn);     // first iter: exp(-inf)=0
        float ex = expf(l - mn);
        m = mn;
        den = den*f + ex;
        const float* hr = h1 + (size_t)s*HID + h*OUT1 + q*3;
        #pragma unroll
        for (int c = 0; c < 3; c++) acc[c] = acc[c]*f + ex*hr[c];
    }
    float inv = 1.f / (den + 1e-16f);
    #pragma unroll
    for (int c = 0; c < 3; c++) x1[(size_t)n*HID + h*OUT1 + q*3 + c] = acc[c]*inv;
}

// ---------- pool-conv1 prep: hp1 = x1@Wp1 (30x32); scalars ----------
__global__ void k_node_proj_p1(const float* __restrict__ x1, const float* __restrict__ Wp1,
                               const float* __restrict__ asp, const float* __restrict__ adp,
                               float* __restrict__ hp1, float* __restrict__ hsp, float* __restrict__ hdp){
    __shared__ float Ws[HID*C1];
    __shared__ float as_s[C1], ad_s[C1];
    for (int i = threadIdx.x; i < HID*C1; i += blockDim.x) Ws[i] = Wp1[i];
    if (threadIdx.x < C1){ as_s[threadIdx.x] = asp[threadIdx.x]; ad_s[threadIdx.x] = adp[threadIdx.x]; }
    __syncthreads();
    int n = blockIdx.x*blockDim.x + threadIdx.x;
    if (n >= NN) return;
    float xv[HID];
    #pragma unroll
    for (int d = 0; d < HID; d++) xv[d] = x1[(size_t)n*HID + d];
    float s = 0.f, dd = 0.f;
    for (int c = 0; c < C1; c++){
        float a = 0.f;
        #pragma unroll
        for (int d = 0; d < HID; d++) a += xv[d]*Ws[d*C1 + c];
        hp1[(size_t)n*C1 + c] = a;
        s += a*as_s[c]; dd += a*ad_s[c];
    }
    hsp[n] = s; hdp[n] = dd;
}

// ---------- pool-conv1 aggregation: online softmax, thread per (node, 4-ch eighth) ----------
__global__ void k_pool1_agg(const int2* __restrict__ se, const int* __restrict__ rowptr,
                            const float* __restrict__ hp1,
                            const float* __restrict__ hsp, const float* __restrict__ hdp,
                            const float* __restrict__ ewp1s, float* __restrict__ s1){
    int tid = blockIdx.x*blockDim.x + threadIdx.x;
    if (tid >= NN*8) return;
    int q = tid & 7;
    int n = tid >> 3;
    int k0 = rowptr[n], k1 = rowptr[n+1];
    float hdv = hdp[n];
    float m = -INFINITY, den = 0.f;
    float acc[4] = {0.f, 0.f, 0.f, 0.f};
    for (int k = k0; k < k1; k++){
        int s = se[k].x;
        float l = lrelu(hsp[s] + hdv + ewp1s[k]);
        float mn = fmaxf(m, l);
        float f  = expf(m - mn);
        float ex = expf(l - mn);
        m = mn;
        den = den*f + ex;
        const float* hr = hp1 + (size_t)s*C1 + q*4;
        #pragma unroll
        for (int c = 0; c < 4; c++) acc[c] = acc[c]*f + ex*hr[c];
    }
    float inv = 1.f / (den + 1e-16f);
    #pragma unroll
    for (int c = 0; c < 4; c++) s1[(size_t)n*C1 + q*4 + c] = acc[c]*inv;
}

// ---------- cluster softmax (over 32) ----------
__global__ void k_soft32(const float* __restrict__ s1, float* __restrict__ ssoft){
    int n = blockIdx.x*blockDim.x + threadIdx.x;
    if (n >= NN) return;
    float v[C1];
    float m = -INFINITY;
    #pragma unroll
    for (int c = 0; c < C1; c++){ v[c] = s1[(size_t)n*C1 + c]; m = fmaxf(m, v[c]); }
    float sum = 0.f;
    #pragma unroll
    for (int c = 0; c < C1; c++){ v[c] = expf(v[c] - m); sum += v[c]; }
    float inv = 1.f/sum;
    #pragma unroll
    for (int c = 0; c < C1; c++) ssoft[(size_t)n*C1 + c] = v[c]*inv;
}

// ---------- T[n,:] = sum over unique out-neighbors m of S[m,:] (thread per (node, eighth)) ----------
__global__ void k_T(const int* __restrict__ rowptrS, const int* __restrict__ unbr,
                    const int* __restrict__ ucnt, const float* __restrict__ ssoft,
                    float* __restrict__ T){
    int tid = blockIdx.x*blockDim.x + threadIdx.x;
    if (tid >= NN*8) return;
    int q = tid & 7;
    int n = tid >> 3;
    int k0 = rowptrS[n];
    int cnt = ucnt[n];
    float acc[4] = {0.f, 0.f, 0.f, 0.f};
    for (int i = 0; i < cnt; i++){
        int m = unbr[k0 + i];
        const float* sr = ssoft + (size_t)m*C1 + q*4;
        #pragma unroll
        for (int c = 0; c < 4; c++) acc[c] += sr[c];
    }
    #pragma unroll
    for (int c = 0; c < 4; c++) T[(size_t)n*C1 + q*4 + c] = acc[c];
}

// ---------- fused partials over 64-node chunks:
//   adj2 += S_chunk^T T_chunk ; G += S_chunk^T S_chunk ; x2 += S_chunk^T X_chunk
__global__ void k_partials(const float* __restrict__ ssoft, const float* __restrict__ T,
                           const float* __restrict__ x1,
                           float* __restrict__ adj2, float* __restrict__ Gm,
                           float* __restrict__ x2){
    int b  = blockIdx.y;
    int n0 = blockIdx.x * 64;
    int t  = threadIdx.x;   // 256
    __shared__ float ssh[64*C1];
    __shared__ float tsh[64*C1];
    __shared__ float xsh[64*HID];
    {
        size_t sbase = ((size_t)b*NPG + n0)*C1;
        #pragma unroll
        for (int i = 0; i < 8; i++){
            int lin = t + i*256;
            ssh[lin] = ssoft[sbase + lin];
            tsh[lin] = T[sbase + lin];
        }
        size_t xbase = ((size_t)b*NPG + n0)*HID;
        for (int lin = t; lin < 64*HID; lin += 256) xsh[lin] = x1[xbase + lin];
    }
    __syncthreads();
    float accA[4] = {0,0,0,0}, accG[4] = {0,0,0,0}, accX[4] = {0,0,0,0};
    int cA[4], kA[4], cX[4], dX[4];
    #pragma unroll
    for (int q = 0; q < 4; q++){
        int p = t + q*256;
        cA[q] = p >> 5; kA[q] = p & 31;
        cX[q] = p / HID; dX[q] = p - cX[q]*HID;   // valid only when p < 960
    }
    for (int r = 0; r < 64; r++){
        const float* sr = ssh + r*C1;
        const float* tr = tsh + r*C1;
        const float* xr = xsh + r*HID;
        #pragma unroll
        for (int q = 0; q < 4; q++){
            float sc = sr[cA[q]];
            accA[q] += sc*tr[kA[q]];
            accG[q] += sc*sr[kA[q]];
        }
        #pragma unroll
        for (int q = 0; q < 4; q++){
            int p = t + q*256;
            if (p < C1*HID) accX[q] += sr[cX[q]]*xr[dX[q]];
        }
    }
    #pragma unroll
    for (int q = 0; q < 4; q++){
        int p = t + q*256;
        atomicAdd(&adj2[(size_t)b*1024 + p], accA[q]);
        atomicAdd(&Gm[(size_t)b*1024 + p], accG[q]);
        if (p < C1*HID) atomicAdd(&x2[((size_t)b*C1 + cX[q])*HID + dX[q]], accX[q]);
    }
}

// ---------- finalize reg1 ingredients: trace(adj2), ||G||_F^2 ----------
__global__ void k_finalize(const float* __restrict__ adj2, const float* __restrict__ Gm,
                           float* __restrict__ scal){
    int b = blockIdx.x;
    int t = threadIdx.x;   // 256
    float ltr = 0.f, lfr = 0.f;
    for (int p = t; p < 1024; p += 256){
        float g = Gm[(size_t)b*1024 + p];
        lfr += g*g;
        if ((p >> 5) == (p & 31)) ltr += adj2[(size_t)b*1024 + p];
    }
    __shared__ float red[256];
    red[t] = ltr; __syncthreads();
    for (int s = 128; s > 0; s >>= 1){ if (t < s) red[t] += red[t+s]; __syncthreads(); }
    if (t == 0) atomicAdd(&scal[1], red[0]);
    __syncthreads();
    red[t] = lfr; __syncthreads();
    for (int s = 128; s > 0; s >>= 1){ if (t < s) red[t] += red[t+s]; __syncthreads(); }
    if (t == 0) atomicAdd(&scal[2], red[0]);
}

// ---------- fused tail: pool-conv2 prep + agg + diffpool2 (graph-local) ----------
__global__ void k_tail(const float* __restrict__ x2, const float* __restrict__ adj2,
                       const float* __restrict__ Wp2, const float* __restrict__ asp,
                       const float* __restrict__ adp, const float* __restrict__ Wep2,
                       float* __restrict__ x3, float* __restrict__ scal){
    int b = blockIdx.x;
    int t = threadIdx.x;  // 256
    __shared__ float x2s[C1*HID];    // 960
    __shared__ float a2s[C1*C1];     // 1024
    __shared__ float Wps[HID*C2];    // 120
    __shared__ float h2s[C1*C2];
    __shared__ float hs2s[C1], hd2s[C1];
    __shared__ float sss[C1*C2];     // softmax(s2)
    __shared__ float red[256];
    for (int i = t; i < C1*HID; i += 256) x2s[i] = x2[(size_t)b*C1*HID + i];
    for (int i = t; i < C1*C1; i += 256) a2s[i] = adj2[(size_t)b*C1*C1 + i];
    if (t < HID*C2) Wps[t] = Wp2[t];
    __syncthreads();
    // phase 1: h2 = x2@Wp2 + attention scalars (32 threads, one per pooled node)
    if (t < C1){
        float s = 0.f, dd = 0.f;
        #pragma unroll
        for (int c = 0; c < C2; c++){
            float a = 0.f;
            #pragma unroll
            for (int d = 0; d < HID; d++) a += x2s[t*HID + d]*Wps[d*C2 + c];
            h2s[t*C2 + c] = a;
            s += a*asp[c]; dd += a*adp[c];
        }
        hs2s[t] = s; hd2s[t] = dd;
    }
    __syncthreads();
    // phase 2: dense EGAT agg over 32 sources + immediate softmax over C2
    if (t < C1){
        int j = t;
        float hdv = hd2s[j];
        float wep = Wep2[0];
        float m = -INFINITY;
        for (int i = 0; i < C1; i++)
            m = fmaxf(m, lrelu(hs2s[i] + hdv + a2s[i*C1 + j]*wep));
        float den = 0.f;
        float acc[C2] = {0,0,0,0};
        for (int i = 0; i < C1; i++){
            float ex = expf(lrelu(hs2s[i] + hdv + a2s[i*C1 + j]*wep) - m);
            den += ex;
            #pragma unroll
            for (int c = 0; c < C2; c++) acc[c] += ex * h2s[i*C2 + c];
        }
        float inv = 1.f/(den + 1e-16f);
        float v[C2]; float mx = -INFINITY;
        #pragma unroll
        for (int c = 0; c < C2; c++){ v[c] = acc[c]*inv; mx = fmaxf(mx, v[c]); }
        float sum = 0.f;
        #pragma unroll
        for (int c = 0; c < C2; c++){ v[c] = expf(v[c] - mx); sum += v[c]; }
        float i2 = 1.f/sum;
        #pragma unroll
        for (int c = 0; c < C2; c++) sss[j*C2 + c] = v[c]*i2;
    }
    __syncthreads();
    // phase 3: x3 = S^T x2 and reg2
    if (t < C2*HID){
        int c = t / HID, d = t % HID;
        float a = 0.f;
        #pragma unroll
        for (int n = 0; n < C1; n++) a += sss[n*C2 + c]*x2s[n*HID + d];
        x3[(size_t)b*C2*HID + t] = a;
    }
    float loc = 0.f;
    for (int p = t; p < 1024; p += 256){
        int n = p >> 5, mm = p & 31;
        float dot = 0.f;
        #pragma unroll
        for (int c = 0; c < C2; c++) dot += sss[n*C2 + c]*sss[mm*C2 + c];
        float df = a2s[p] - dot;
        loc += df*df;
    }
    red[t] = loc; __syncthreads();
    for (int s = 128; s > 0; s >>= 1){ if (t < s) red[t] += red[t+s]; __syncthreads(); }
    if (t == 0) atomicAdd(&scal[3], red[0]);
}

// ---------- final MLP + reg assembly ----------
__global__ void k_mlp(const float* __restrict__ x3, const float* __restrict__ Wf1,
                      const float* __restrict__ bf1, const float* __restrict__ Wf2,
                      const float* __restrict__ bf2, const float* __restrict__ scal,
                      float* __restrict__ out){
    __shared__ float zsh[NB*32];
    int t = threadIdx.x;   // 512
    if (t < NB*32){
        int b = t >> 5, j = t & 31;
        float a = bf1[j];
        const float* xr = x3 + (size_t)b*C2*HID;
        #pragma unroll 4
        for (int k = 0; k < C2*HID; k++) a += xr[k]*Wf1[k*32 + j];
        zsh[t] = fmaxf(a, 0.f);
    }
    __syncthreads();
    if (t < NB*2){
        int b = t >> 1, o = t & 1;
        float a = bf2[o];
        #pragma unroll
        for (int j = 0; j < 32; j++) a += zsh[b*32 + j]*Wf2[j*2 + o];
        out[t] = a;
    }
    if (t == 0){
        float adjsum = scal[0], tr = scal[1], fr = scal[2], r2 = scal[3];
        float reg1 = (adjsum - 2.f*tr + fr) * (1.f/16777216.f);
        float reg2 = r2 * (1.f/16384.f);
        out[32] = 10.f*reg1 + 0.1f*reg2;
    }
}

extern "C" void kernel_launch(void* const* d_in, const int* in_sizes, int n_in,
                              void* d_out, int out_size, void* d_ws, size_t ws_size,
                              hipStream_t stream) {
    const float* x    = (const float*)d_in[0];
    const int*   ei   = (const int*)d_in[1];
    const float* ea   = (const float*)d_in[2];
    // d_in[3] = y (unused); d_in[4] = adj (algebraically eliminated — never read)
    const float* W1   = (const float*)d_in[5];
    const float* as1  = (const float*)d_in[6];
    const float* ad1  = (const float*)d_in[7];
    const float* We1  = (const float*)d_in[8];
    const float* Wp1  = (const float*)d_in[9];
    const float* asp1 = (const float*)d_in[10];
    const float* adp1 = (const float*)d_in[11];
    const float* Wep1 = (const float*)d_in[12];
    const float* Wp2  = (const float*)d_in[13];
    const float* asp2 = (const float*)d_in[14];
    const float* adp2 = (const float*)d_in[15];
    const float* Wep2 = (const float*)d_in[16];
    const float* Wf1  = (const float*)d_in[17];
    const float* bf1  = (const float*)d_in[18];
    const float* Wf2  = (const float*)d_in[19];
    const float* bf2  = (const float*)d_in[20];
    float* out = (float*)d_out;

    const int* srcA = ei;
    const int* dstA = ei + EE;

    char* wp = (char*)d_ws;
    auto carve = [&](size_t bytes)->char*{
        char* p = wp;
        wp += (bytes + 255) & ~(size_t)255;
        return p;
    };
    float* h1    = (float*)carve((size_t)NN*HID*4);
    float* hs1   = (float*)carve((size_t)NN*NHEADS*4);
    float* hd1   = (float*)carve((size_t)NN*NHEADS*4);
    float* ew1s  = (float*)carve((size_t)EE*NHEADS*4);
    float* ewp1s = (float*)carve((size_t)EE*4);
    float* x1    = (float*)carve((size_t)NN*HID*4);
    float* hp1   = (float*)carve((size_t)NN*C1*4);
    float* hsp   = (float*)carve((size_t)NN*4);
    float* hdp   = (float*)carve((size_t)NN*4);
    float* s1    = (float*)carve((size_t)NN*C1*4);
    float* ssoft = (float*)carve((size_t)NN*C1*4);
    float* T     = (float*)carve((size_t)NN*C1*4);
    // --- zero-init region (contiguous): x2, adj2, Gm ---
    float* x2    = (float*)carve((size_t)NB*C1*HID*4);   // 61440 B (256-aligned)
    float* adj2  = (float*)carve((size_t)NB*C1*C1*4);    // 65536 B
    float* Gm    = (float*)carve((size_t)NB*C1*C1*4);    // 65536 B
    // ---------------------------------------------------
    float* x3    = (float*)carve((size_t)NB*C2*HID*4);
    float* scal  = (float*)carve(16*4);
    int* histD   = (int*)carve((size_t)NB*CH*NPG*4);     // 1 MB
    int* histS   = (int*)carve((size_t)NB*CH*NPG*4);     // 1 MB
    int* deg     = (int*)carve((size_t)NN*4);
    int* degS    = (int*)carve((size_t)NN*4);
    int* rowptr  = (int*)carve((size_t)(NN+1)*4);
    int* rowptrS = (int*)carve((size_t)(NN+1)*4);
    int2* se     = (int2*)carve((size_t)EE*8);
    int* nbrS    = (int*)carve((size_t)EE*4);
    int* unbr    = (int*)carve((size_t)EE*4);
    int* ucnt    = (int*)carve((size_t)NN*4);

    hipMemsetAsync(scal, 0, 16*4, stream);
    hipMemsetAsync(x2, 0, (size_t)(NB*C1*HID + 2*NB*C1*C1)*4, stream);  // x2+adj2+Gm

    const int TB = 256;
    dim3 gN((NN + TB - 1)/TB);

    // merged: per-chunk dual LDS histograms (256 blocks) + node projection (64 blocks)
    k_hist_chunk<<<dim3(256 + 64), TB, 0, stream>>>(srcA, dstA, histD, histS,
                                                    x, W1, as1, ad1, h1, hs1, hd1);
    // per-(g,n) chunk scan (in place) + deg/degS
    k_cumhist<<<dim3(128), TB, 0, stream>>>(histD, histS, deg, degS);
    // node-level scans -> rowptr/rowptrS
    k_scan2f<<<dim3(2), 1024, 0, stream>>>(deg, degS, rowptr, rowptrS);
    // deterministic scatter (LDS atomics only)
    k_scatter_det<<<dim3(256), TB, 0, stream>>>(srcA, dstA, rowptr, rowptrS,
                                                histD, histS, se, nbrS);

    // merged: edge projections (2048 blocks) + dedup (64 blocks)
    k_proj_dedup<<<dim3(2048 + 64), TB, 0, stream>>>(ea, We1, Wep1, se, ew1s, ewp1s,
                                                     rowptrS, nbrS, unbr, ucnt, scal);

    // conv1: thread per (node, head, 3-ch half), single-pass online softmax
    k_conv1_agg<<<dim3(NN*NHEADS*2/TB), TB, 0, stream>>>(se, rowptr, h1, hs1, hd1, ew1s, x1);

    // pool-conv1
    k_node_proj_p1<<<gN, TB, 0, stream>>>(x1, Wp1, asp1, adp1, hp1, hsp, hdp);
    k_pool1_agg<<<dim3(NN*8/TB), TB, 0, stream>>>(se, rowptr, hp1, hsp, hdp, ewp1s, s1);

    // diffpool1
    k_soft32<<<gN, TB, 0, stream>>>(s1, ssoft);
    k_T<<<dim3(NN*8/TB), TB, 0, stream>>>(rowptrS, unbr, ucnt, ssoft, T);
    k_partials<<<dim3(16, NB), TB, 0, stream>>>(ssoft, T, x1, adj2, Gm, x2);
    k_finalize<<<dim3(NB), TB, 0, stream>>>(adj2, Gm, scal);

    // fused tail: pool-conv2 + diffpool2 + reg2
    k_tail<<<dim3(NB), TB, 0, stream>>>(x2, adj2, Wp2, asp2, adp2, Wep2, x3, scal);

    // MLP + output
    k_mlp<<<1, 512, 0, stream>>>(x3, Wf1, bf1, Wf2, bf2, scal, out);
}

// Round 11
// 298.770 us; speedup vs baseline: 1.5600x; 1.1115x over previous
//
#include <hip/hip_runtime.h>
#include <math.h>

#define NB 16
#define NPG 1024
#define DIN 16
#define ED 8
#define NHEADS 5
#define OUT1 6
#define HID 30
#define C1 32
#define C2 4
#define NN (NB*NPG)      // 16384 nodes
#define EE (NN*32)       // 524288 edges
#define EPG 32768        // edges per graph (graph-contiguous in edge_index)
#define CH 16            // chunks per graph
#define CE 2048          // edges per chunk

__device__ __forceinline__ float lrelu(float v){ return v >= 0.f ? v : 0.2f*v; }

// chunk mapping for 256-block edge kernels: XCD-affine, block -> (g, c)
__device__ __forceinline__ void chunk_gc(int& g, int& c){
    int x = blockIdx.x & 7;
    int j = blockIdx.x >> 3;     // 0..31
    g = x + 8*(j >> 4);          // 2 graphs per XCD
    c = j & 15;
}

// XCD-affinity mapping for 2048-block edge kernels (edge projections)
__device__ __forceinline__ size_t xcd_chunk_base(){
    int x = blockIdx.x & 7;
    int j = blockIdx.x >> 3;            // 0..255 position within this XCD
    int g = x + 8*(j >> 7);             // 2 graphs per XCD
    int c = j & 127;                    // 128 chunks per graph
    return (size_t)g*EPG + (size_t)c*256;
}

// ---------- merged: per-chunk dual LDS histograms (blocks 0..255) + node projection ----------
__global__ void k_hist_chunk(const int* __restrict__ src, const int* __restrict__ dst,
                             int* __restrict__ histD, int* __restrict__ histS,
                             const float* __restrict__ x, const float* __restrict__ W1,
                             const float* __restrict__ as1, const float* __restrict__ ad1,
                             float* __restrict__ h1, float* __restrict__ hs1, float* __restrict__ hd1){
    int t = threadIdx.x;
    if (blockIdx.x < 256){
        __shared__ int hD[NPG], hS[NPG];
        for (int i = t; i < NPG; i += 256){ hD[i] = 0; hS[i] = 0; }
        __syncthreads();
        int g, c; chunk_gc(g, c);
        size_t e0 = ((size_t)g*CH + c)*CE;
        #pragma unroll
        for (int i = 0; i < 8; i++){
            size_t e = e0 + i*256 + t;
            atomicAdd(&hD[dst[e] & (NPG-1)], 1);
            atomicAdd(&hS[src[e] & (NPG-1)], 1);
        }
        __syncthreads();
        size_t hb = ((size_t)g*CH + c)*NPG;
        for (int i = t; i < NPG; i += 256){
            histD[hb + i] = hD[i];
            histS[hb + i] = hS[i];
        }
        return;
    }
    // node projection part (blocks 256..319)
    __shared__ float Ws[DIN*HID];
    __shared__ float as_s[HID], ad_s[HID];
    for (int i = t; i < DIN*HID; i += blockDim.x) Ws[i] = W1[i];
    if (t < HID){ as_s[t] = as1[t]; ad_s[t] = ad1[t]; }
    __syncthreads();
    int n = (blockIdx.x - 256)*blockDim.x + t;
    if (n >= NN) return;
    float xv[DIN];
    #pragma unroll
    for (int i = 0; i < DIN; i++) xv[i] = x[n*DIN + i];
    float hv[HID];
    #pragma unroll
    for (int j = 0; j < HID; j++){
        float a = 0.f;
        #pragma unroll
        for (int i = 0; i < DIN; i++) a += xv[i]*Ws[i*HID + j];
        hv[j] = a; h1[(size_t)n*HID + j] = a;
    }
    #pragma unroll
    for (int h = 0; h < NHEADS; h++){
        float s = 0.f, d = 0.f;
        #pragma unroll
        for (int c2 = 0; c2 < OUT1; c2++){ s += hv[h*OUT1+c2]*as_s[h*OUT1+c2]; d += hv[h*OUT1+c2]*ad_s[h*OUT1+c2]; }
        hs1[n*NHEADS + h] = s; hd1[n*NHEADS + h] = d;
    }
}

// ---------- per-(g,n) exclusive scan over chunks, in place; emits deg ----------
__global__ void k_cumhist(int* __restrict__ histD, int* __restrict__ histS,
                          int* __restrict__ deg, int* __restrict__ degS){
    int tid = blockIdx.x*blockDim.x + threadIdx.x;
    int* hist; int* dg;
    if (tid < NN){ hist = histD; dg = deg; }
    else         { hist = histS; dg = degS; tid -= NN; }
    int g = tid >> 10, n = tid & (NPG-1);
    int run = 0;
    #pragma unroll
    for (int c = 0; c < CH; c++){
        size_t idx = ((size_t)g*CH + c)*NPG + n;
        int v = hist[idx];
        hist[idx] = run;
        run += v;
    }
    dg[tid] = run;
}

// ---------- both exclusive scans: 2 blocks, wave-shfl scan ----------
__global__ __launch_bounds__(1024) void k_scan2f(const int* __restrict__ deg,
                        const int* __restrict__ degS,
                        int* __restrict__ rowptr, int* __restrict__ rowptrS){
    __shared__ int wtot[16];
    __shared__ int wbase[16];
    const int* d = (blockIdx.x == 0) ? deg    : degS;
    int* rp      = (blockIdx.x == 0) ? rowptr : rowptrS;
    int t = threadIdx.x;
    int lane = t & 63, wv = t >> 6;
    int base = t*16;
    int loc[16]; int tot = 0;
    #pragma unroll
    for (int i = 0; i < 16; i++){ loc[i] = tot; tot += d[base + i]; }
    int sincl = tot;                       // wave-inclusive scan of thread totals
    #pragma unroll
    for (int off = 1; off < 64; off <<= 1){
        int v = __shfl_up(sincl, off, 64);
        if (lane >= off) sincl += v;
    }
    if (lane == 63) wtot[wv] = sincl;
    __syncthreads();
    if (t == 0){
        int run = 0;
        #pragma unroll
        for (int w = 0; w < 16; w++){ wbase[w] = run; run += wtot[w]; }
    }
    __syncthreads();
    int gexcl = wbase[wv] + sincl - tot;   // global exclusive prefix for this thread
    #pragma unroll
    for (int i = 0; i < 16; i++) rp[base + i] = gexcl + loc[i];
    if (t == 1023) rp[NN] = gexcl + tot;
}

// ---------- deterministic scatter: slot = rowptr + chunk-base + LDS rank (no global atomics) ----------
__global__ void k_scatter_det(const int* __restrict__ src, const int* __restrict__ dst,
                              const int* __restrict__ rowptr, const int* __restrict__ rowptrS,
                              const int* __restrict__ histD, const int* __restrict__ histS,
                              int2* __restrict__ se, int* __restrict__ nbrS){
    __shared__ int baseD[NPG], baseS[NPG];
    int t = threadIdx.x;
    int g, c; chunk_gc(g, c);
    size_t hb = ((size_t)g*CH + c)*NPG;
    for (int i = t; i < NPG; i += 256){
        baseD[i] = rowptr[g*NPG + i] + histD[hb + i];
        baseS[i] = rowptrS[g*NPG + i] + histS[hb + i];
    }
    __syncthreads();
    size_t e0 = ((size_t)g*CH + c)*CE;
    #pragma unroll
    for (int i = 0; i < 8; i++){
        size_t e = e0 + i*256 + t;
        int s = src[e], d = dst[e];
        int p = atomicAdd(&baseD[d & (NPG-1)], 1);
        se[p] = make_int2(s, (int)e);
        int pS = atomicAdd(&baseS[s & (NPG-1)], 1);
        nbrS[pS] = d;
    }
}

// ---------- merged: edge projections (blocks 0..2047) + dedup (2048..2111) ----------
__global__ void k_proj_dedup(const float* __restrict__ ea, const float* __restrict__ We1,
                             const float* __restrict__ Wep1, const int2* __restrict__ se,
                             float* __restrict__ ew1s, float* __restrict__ ewp1s,
                             const int* __restrict__ rowptrS, const int* __restrict__ nbrS,
                             int* __restrict__ unbr, int* __restrict__ ucnt,
                             float* __restrict__ scal){
    __shared__ unsigned int bm[256*33];   // dedup bitmap (33-word stride)
    __shared__ int red[256];
    __shared__ float W[ED*NHEADS];
    __shared__ float Wp[ED];
    int t = threadIdx.x;
    if (blockIdx.x < 2048){
        if (t < ED*NHEADS) W[t] = We1[t];
        if (t < ED) Wp[t] = Wep1[t];
        __syncthreads();
        size_t k = xcd_chunk_base() + t;
        int e = se[k].y;
        float a[ED];
        #pragma unroll
        for (int i = 0; i < ED; i++) a[i] = ea[(size_t)e*ED + i];
        #pragma unroll
        for (int h = 0; h < NHEADS; h++){
            float s = 0.f;
            #pragma unroll
            for (int i = 0; i < ED; i++) s += a[i]*W[i*NHEADS + h];
            ew1s[k*NHEADS + h] = s;
        }
        float s = 0.f;
        #pragma unroll
        for (int i = 0; i < ED; i++) s += a[i]*Wp[i];
        ewp1s[k] = s;
        return;
    }
    // dedup via per-thread LDS bitmap (neighbors are block-local 0..1023)
    unsigned int* mybm = &bm[t*33];
    #pragma unroll
    for (int i = 0; i < 32; i++) mybm[i] = 0u;
    int n = (blockIdx.x - 2048)*blockDim.x + t;
    int cnt = 0;
    if (n < NN){
        int k0 = rowptrS[n], k1 = rowptrS[n+1];
        for (int k = k0; k < k1; k++){
            int m = nbrS[k];
            int loc = m & (NPG-1);
            unsigned int w = (unsigned int)(loc >> 5);
            unsigned int bit = 1u << (loc & 31);
            unsigned int old = mybm[w];
            if (!(old & bit)){
                mybm[w] = old | bit;
                unbr[k0 + cnt] = m;
                cnt++;
            }
        }
        ucnt[n] = cnt;
    }
    red[t] = cnt; __syncthreads();
    for (int s = 128; s > 0; s >>= 1){ if (t < s) red[t] += red[t+s]; __syncthreads(); }
    if (t == 0) atomicAdd(&scal[0], (float)red[0]);
}

// ---------- conv1 aggregation: batched-4 online softmax, thread per (node, head, 3-ch half) ----------
__global__ void k_conv1_agg(const int2* __restrict__ se, const int* __restrict__ rowptr,
                            const float* __restrict__ h1,
                            const float* __restrict__ hs1, const float* __restrict__ hd1,
                            const float* __restrict__ ew1s, float* __restrict__ x1){
    int tid = blockIdx.x*blockDim.x + threadIdx.x;
    if (tid >= NN*NHEADS*2) return;
    int n = tid / (NHEADS*2);
    int r = tid - n*(NHEADS*2);
    int h = r >> 1;
    int q = r & 1;               // 3-channel half
    int k0 = rowptr[n], k1 = rowptr[n+1];
    float hdv = hd1[n*NHEADS + h];
    float m = -INFINITY, den = 0.f;
    float acc[3] = {0.f, 0.f, 0.f};
    int k = k0;
    for (; k + 4 <= k1; k += 4){
        int s0 = se[k+0].x, s1 = se[k+1].x, s2 = se[k+2].x, s3 = se[k+3].x;
        float w0 = ew1s[(size_t)(k+0)*NHEADS + h];
        float w1 = ew1s[(size_t)(k+1)*NHEADS + h];
        float w2 = ew1s[(size_t)(k+2)*NHEADS + h];
        float w3 = ew1s[(size_t)(k+3)*NHEADS + h];
        float l0 = lrelu(hs1[s0*NHEADS + h] + hdv + w0);
        float l1 = lrelu(hs1[s1*NHEADS + h] + hdv + w1);
        float l2 = lrelu(hs1[s2*NHEADS + h] + hdv + w2);
        float l3 = lrelu(hs1[s3*NHEADS + h] + hdv + w3);
        const float* p0 = h1 + (size_t)s0*HID + h*OUT1 + q*3;
        const float* p1 = h1 + (size_t)s1*HID + h*OUT1 + q*3;
        const float* p2 = h1 + (size_t)s2*HID + h*OUT1 + q*3;
        const float* p3 = h1 + (size_t)s3*HID + h*OUT1 + q*3;
        float mb = fmaxf(fmaxf(l0, l1), fmaxf(l2, l3));
        float mn = fmaxf(m, mb);
        float f  = expf(m - mn);       // first batch: exp(-inf)=0
        float e0 = expf(l0 - mn), e1 = expf(l1 - mn);
        float e2 = expf(l2 - mn), e3 = expf(l3 - mn);
        m = mn;
        den = den*f + e0 + e1 + e2 + e3;
        #pragma unroll
        for (int c = 0; c < 3; c++)
            acc[c] = acc[c]*f + e0*p0[c] + e1*p1[c] + e2*p2[c] + e3*p3[c];
    }
    for (; k < k1; k++){
        int s = se[k].x;
        float l = lrelu(hs1[s*NHEADS + h] + hdv + ew1s[(size_t)k*NHEADS + h]);
        float mn = fmaxf(m, l);
        float f  = expf(m - mn);
        float ex = expf(l - mn);
        m = mn;
        den = den*f + ex;
        const float* hr = h1 + (size_t)s*HID + h*OUT1 + q*3;
        #pragma unroll
        for (int c = 0; c < 3; c++) acc[c] = acc[c]*f + ex*hr[c];
    }
    float inv = 1.f / (den + 1e-16f);
    #pragma unroll
    for (int c = 0; c < 3; c++) x1[(size_t)n*HID + h*OUT1 + q*3 + c] = acc[c]*inv;
}

// ---------- pool-conv1 prep: hp1 = x1@Wp1 (30x32); scalars ----------
__global__ void k_node_proj_p1(const float* __restrict__ x1, const float* __restrict__ Wp1,
                               const float* __restrict__ asp, const float* __restrict__ adp,
                               float* __restrict__ hp1, float* __restrict__ hsp, float* __restrict__ hdp){
    __shared__ float Ws[HID*C1];
    __shared__ float as_s[C1], ad_s[C1];
    for (int i = threadIdx.x; i < HID*C1; i += blockDim.x) Ws[i] = Wp1[i];
    if (threadIdx.x < C1){ as_s[threadIdx.x] = asp[threadIdx.x]; ad_s[threadIdx.x] = adp[threadIdx.x]; }
    __syncthreads();
    int n = blockIdx.x*blockDim.x + threadIdx.x;
    if (n >= NN) return;
    float xv[HID];
    #pragma unroll
    for (int d = 0; d < HID; d++) xv[d] = x1[(size_t)n*HID + d];
    float s = 0.f, dd = 0.f;
    for (int c = 0; c < C1; c++){
        float a = 0.f;
        #pragma unroll
        for (int d = 0; d < HID; d++) a += xv[d]*Ws[d*C1 + c];
        hp1[(size_t)n*C1 + c] = a;
        s += a*as_s[c]; dd += a*ad_s[c];
    }
    hsp[n] = s; hdp[n] = dd;
}

// ---------- pool-conv1 aggregation: batched-4, thread per (node, 4-ch eighth) ----------
__global__ void k_pool1_agg(const int2* __restrict__ se, const int* __restrict__ rowptr,
                            const float* __restrict__ hp1,
                            const float* __restrict__ hsp, const float* __restrict__ hdp,
                            const float* __restrict__ ewp1s, float* __restrict__ s1){
    int tid = blockIdx.x*blockDim.x + threadIdx.x;
    if (tid >= NN*8) return;
    int q = tid & 7;
    int n = tid >> 3;
    int k0 = rowptr[n], k1 = rowptr[n+1];
    float hdv = hdp[n];
    float m = -INFINITY, den = 0.f;
    float acc[4] = {0.f, 0.f, 0.f, 0.f};
    int k = k0;
    for (; k + 4 <= k1; k += 4){
        int s0 = se[k+0].x, s1 = se[k+1].x, s2 = se[k+2].x, s3 = se[k+3].x;
        float w0 = ewp1s[k+0], w1 = ewp1s[k+1], w2 = ewp1s[k+2], w3 = ewp1s[k+3];
        float l0 = lrelu(hsp[s0] + hdv + w0);
        float l1 = lrelu(hsp[s1] + hdv + w1);
        float l2 = lrelu(hsp[s2] + hdv + w2);
        float l3 = lrelu(hsp[s3] + hdv + w3);
        float4 v0 = *(const float4*)(hp1 + (size_t)s0*C1 + q*4);
        float4 v1 = *(const float4*)(hp1 + (size_t)s1*C1 + q*4);
        float4 v2 = *(const float4*)(hp1 + (size_t)s2*C1 + q*4);
        float4 v3 = *(const float4*)(hp1 + (size_t)s3*C1 + q*4);
        float mb = fmaxf(fmaxf(l0, l1), fmaxf(l2, l3));
        float mn = fmaxf(m, mb);
        float f  = expf(m - mn);
        float e0 = expf(l0 - mn), e1 = expf(l1 - mn);
        float e2 = expf(l2 - mn), e3 = expf(l3 - mn);
        m = mn;
        den = den*f + e0 + e1 + e2 + e3;
        acc[0] = acc[0]*f + e0*v0.x + e1*v1.x + e2*v2.x + e3*v3.x;
        acc[1] = acc[1]*f + e0*v0.y + e1*v1.y + e2*v2.y + e3*v3.y;
        acc[2] = acc[2]*f + e0*v0.z + e1*v1.z + e2*v2.z + e3*v3.z;
        acc[3] = acc[3]*f + e0*v0.w + e1*v1.w + e2*v2.w + e3*v3.w;
    }
    for (; k < k1; k++){
        int s = se[k].x;
        float l = lrelu(hsp[s] + hdv + ewp1s[k]);
        float mn = fmaxf(m, l);
        float f  = expf(m - mn);
        float ex = expf(l - mn);
        m = mn;
        den = den*f + ex;
        const float* hr = hp1 + (size_t)s*C1 + q*4;
        #pragma unroll
        for (int c = 0; c < 4; c++) acc[c] = acc[c]*f + ex*hr[c];
    }
    float inv = 1.f / (den + 1e-16f);
    #pragma unroll
    for (int c = 0; c < 4; c++) s1[(size_t)n*C1 + q*4 + c] = acc[c]*inv;
}

// ---------- cluster softmax (over 32) ----------
__global__ void k_soft32(const float* __restrict__ s1, float* __restrict__ ssoft){
    int n = blockIdx.x*blockDim.x + threadIdx.x;
    if (n >= NN) return;
    float v[C1];
    float m = -INFINITY;
    #pragma unroll
    for (int c = 0; c < C1; c++){ v[c] = s1[(size_t)n*C1 + c]; m = fmaxf(m, v[c]); }
    float sum = 0.f;
    #pragma unroll
    for (int c = 0; c < C1; c++){ v[c] = expf(v[c] - m); sum += v[c]; }
    float inv = 1.f/sum;
    #pragma unroll
    for (int c = 0; c < C1; c++) ssoft[(size_t)n*C1 + c] = v[c]*inv;
}

// ---------- T[n,:] = sum over unique out-neighbors, batched-4 float4 gathers ----------
__global__ void k_T(const int* __restrict__ rowptrS, const int* __restrict__ unbr,
                    const int* __restrict__ ucnt, const float* __restrict__ ssoft,
                    float* __restrict__ T){
    int tid = blockIdx.x*blockDim.x + threadIdx.x;
    if (tid >= NN*8) return;
    int q = tid & 7;
    int n = tid >> 3;
    int k0 = rowptrS[n];
    int cnt = ucnt[n];
    float acc[4] = {0.f, 0.f, 0.f, 0.f};
    int i = 0;
    for (; i + 4 <= cnt; i += 4){
        int m0 = unbr[k0+i+0], m1 = unbr[k0+i+1], m2 = unbr[k0+i+2], m3 = unbr[k0+i+3];
        float4 v0 = *(const float4*)(ssoft + (size_t)m0*C1 + q*4);
        float4 v1 = *(const float4*)(ssoft + (size_t)m1*C1 + q*4);
        float4 v2 = *(const float4*)(ssoft + (size_t)m2*C1 + q*4);
        float4 v3 = *(const float4*)(ssoft + (size_t)m3*C1 + q*4);
        acc[0] += v0.x + v1.x + v2.x + v3.x;
        acc[1] += v0.y + v1.y + v2.y + v3.y;
        acc[2] += v0.z + v1.z + v2.z + v3.z;
        acc[3] += v0.w + v1.w + v2.w + v3.w;
    }
    for (; i < cnt; i++){
        int m = unbr[k0 + i];
        const float* sr = ssoft + (size_t)m*C1 + q*4;
        #pragma unroll
        for (int c = 0; c < 4; c++) acc[c] += sr[c];
    }
    #pragma unroll
    for (int c = 0; c < 4; c++) T[(size_t)n*C1 + q*4 + c] = acc[c];
}

// ---------- fused partials over 64-node chunks ----------
__global__ void k_partials(const float* __restrict__ ssoft, const float* __restrict__ T,
                           const float* __restrict__ x1,
                           float* __restrict__ adj2, float* __restrict__ Gm,
                           float* __restrict__ x2){
    int b  = blockIdx.y;
    int n0 = blockIdx.x * 64;
    int t  = threadIdx.x;   // 256
    __shared__ float ssh[64*C1];
    __shared__ float tsh[64*C1];
    __shared__ float xsh[64*HID];
    {
        size_t sbase = ((size_t)b*NPG + n0)*C1;
        #pragma unroll
        for (int i = 0; i < 8; i++){
            int lin = t + i*256;
            ssh[lin] = ssoft[sbase + lin];
            tsh[lin] = T[sbase + lin];
        }
        size_t xbase = ((size_t)b*NPG + n0)*HID;
        for (int lin = t; lin < 64*HID; lin += 256) xsh[lin] = x1[xbase + lin];
    }
    __syncthreads();
    float accA[4] = {0,0,0,0}, accG[4] = {0,0,0,0}, accX[4] = {0,0,0,0};
    int cA[4], kA[4], cX[4], dX[4];
    #pragma unroll
    for (int q = 0; q < 4; q++){
        int p = t + q*256;
        cA[q] = p >> 5; kA[q] = p & 31;
        cX[q] = p / HID; dX[q] = p - cX[q]*HID;   // valid only when p < 960
    }
    for (int r = 0; r < 64; r++){
        const float* sr = ssh + r*C1;
        const float* tr = tsh + r*C1;
        const float* xr = xsh + r*HID;
        #pragma unroll
        for (int q = 0; q < 4; q++){
            float sc = sr[cA[q]];
            accA[q] += sc*tr[kA[q]];
            accG[q] += sc*sr[kA[q]];
        }
        #pragma unroll
        for (int q = 0; q < 4; q++){
            int p = t + q*256;
            if (p < C1*HID) accX[q] += sr[cX[q]]*xr[dX[q]];
        }
    }
    #pragma unroll
    for (int q = 0; q < 4; q++){
        int p = t + q*256;
        atomicAdd(&adj2[(size_t)b*1024 + p], accA[q]);
        atomicAdd(&Gm[(size_t)b*1024 + p], accG[q]);
        if (p < C1*HID) atomicAdd(&x2[((size_t)b*C1 + cX[q])*HID + dX[q]], accX[q]);
    }
}

// ---------- finalize reg1 ingredients: trace(adj2), ||G||_F^2 ----------
__global__ void k_finalize(const float* __restrict__ adj2, const float* __restrict__ Gm,
                           float* __restrict__ scal){
    int b = blockIdx.x;
    int t = threadIdx.x;   // 256
    float ltr = 0.f, lfr = 0.f;
    for (int p = t; p < 1024; p += 256){
        float g = Gm[(size_t)b*1024 + p];
        lfr += g*g;
        if ((p >> 5) == (p & 31)) ltr += adj2[(size_t)b*1024 + p];
    }
    __shared__ float red[256];
    red[t] = ltr; __syncthreads();
    for (int s = 128; s > 0; s >>= 1){ if (t < s) red[t] += red[t+s]; __syncthreads(); }
    if (t == 0) atomicAdd(&scal[1], red[0]);
    __syncthreads();
    red[t] = lfr; __syncthreads();
    for (int s = 128; s > 0; s >>= 1){ if (t < s) red[t] += red[t+s]; __syncthreads(); }
    if (t == 0) atomicAdd(&scal[2], red[0]);
}

// ---------- fused tail: pool-conv2 prep + agg + diffpool2 (graph-local) ----------
__global__ void k_tail(const float* __restrict__ x2, const float* __restrict__ adj2,
                       const float* __restrict__ Wp2, const float* __restrict__ asp,
                       const float* __restrict__ adp, const float* __restrict__ Wep2,
                       float* __restrict__ x3, float* __restrict__ scal){
    int b = blockIdx.x;
    int t = threadIdx.x;  // 256
    __shared__ float x2s[C1*HID];    // 960
    __shared__ float a2s[C1*C1];     // 1024
    __shared__ float Wps[HID*C2];    // 120
    __shared__ float h2s[C1*C2];
    __shared__ float hs2s[C1], hd2s[C1];
    __shared__ float sss[C1*C2];     // softmax(s2)
    __shared__ float red[256];
    for (int i = t; i < C1*HID; i += 256) x2s[i] = x2[(size_t)b*C1*HID + i];
    for (int i = t; i < C1*C1; i += 256) a2s[i] = adj2[(size_t)b*C1*C1 + i];
    if (t < HID*C2) Wps[t] = Wp2[t];
    __syncthreads();
    if (t < C1){
        float s = 0.f, dd = 0.f;
        #pragma unroll
        for (int c = 0; c < C2; c++){
            float a = 0.f;
            #pragma unroll
            for (int d = 0; d < HID; d++) a += x2s[t*HID + d]*Wps[d*C2 + c];
            h2s[t*C2 + c] = a;
            s += a*asp[c]; dd += a*adp[c];
        }
        hs2s[t] = s; hd2s[t] = dd;
    }
    __syncthreads();
    if (t < C1){
        int j = t;
        float hdv = hd2s[j];
        float wep = Wep2[0];
        float m = -INFINITY;
        for (int i = 0; i < C1; i++)
            m = fmaxf(m, lrelu(hs2s[i] + hdv + a2s[i*C1 + j]*wep));
        float den = 0.f;
        float acc[C2] = {0,0,0,0};
        for (int i = 0; i < C1; i++){
            float ex = expf(lrelu(hs2s[i] + hdv + a2s[i*C1 + j]*wep) - m);
            den += ex;
            #pragma unroll
            for (int c = 0; c < C2; c++) acc[c] += ex * h2s[i*C2 + c];
        }
        float inv = 1.f/(den + 1e-16f);
        float v[C2]; float mx = -INFINITY;
        #pragma unroll
        for (int c = 0; c < C2; c++){ v[c] = acc[c]*inv; mx = fmaxf(mx, v[c]); }
        float sum = 0.f;
        #pragma unroll
        for (int c = 0; c < C2; c++){ v[c] = expf(v[c] - mx); sum += v[c]; }
        float i2 = 1.f/sum;
        #pragma unroll
        for (int c = 0; c < C2; c++) sss[j*C2 + c] = v[c]*i2;
    }
    __syncthreads();
    if (t < C2*HID){
        int c = t / HID, d = t % HID;
        float a = 0.f;
        #pragma unroll
        for (int n = 0; n < C1; n++) a += sss[n*C2 + c]*x2s[n*HID + d];
        x3[(size_t)b*C2*HID + t] = a;
    }
    float loc = 0.f;
    for (int p = t; p < 1024; p += 256){
        int n = p >> 5, mm = p & 31;
        float dot = 0.f;
        #pragma unroll
        for (int c = 0; c < C2; c++) dot += sss[n*C2 + c]*sss[mm*C2 + c];
        float df = a2s[p] - dot;
        loc += df*df;
    }
    red[t] = loc; __syncthreads();
    for (int s = 128; s > 0; s >>= 1){ if (t < s) red[t] += red[t+s]; __syncthreads(); }
    if (t == 0) atomicAdd(&scal[3], red[0]);
}

// ---------- final MLP + reg assembly ----------
__global__ void k_mlp(const float* __restrict__ x3, const float* __restrict__ Wf1,
                      const float* __restrict__ bf1, const float* __restrict__ Wf2,
                      const float* __restrict__ bf2, const float* __restrict__ scal,
                      float* __restrict__ out){
    __shared__ float zsh[NB*32];
    int t = threadIdx.x;   // 512
    if (t < NB*32){
        int b = t >> 5, j = t & 31;
        float a = bf1[j];
        const float* xr = x3 + (size_t)b*C2*HID;
        #pragma unroll 4
        for (int k = 0; k < C2*HID; k++) a += xr[k]*Wf1[k*32 + j];
        zsh[t] = fmaxf(a, 0.f);
    }
    __syncthreads();
    if (t < NB*2){
        int b = t >> 1, o = t & 1;
        float a = bf2[o];
        #pragma unroll
        for (int j = 0; j < 32; j++) a += zsh[b*32 + j]*Wf2[j*2 + o];
        out[t] = a;
    }
    if (t == 0){
        float adjsum = scal[0], tr = scal[1], fr = scal[2], r2 = scal[3];
        float reg1 = (adjsum - 2.f*tr + fr) * (1.f/16777216.f);
        float reg2 = r2 * (1.f/16384.f);
        out[32] = 10.f*reg1 + 0.1f*reg2;
    }
}

extern "C" void kernel_launch(void* const* d_in, const int* in_sizes, int n_in,
                              void* d_out, int out_size, void* d_ws, size_t ws_size,
                              hipStream_t stream) {
    const float* x    = (const float*)d_in[0];
    const int*   ei   = (const int*)d_in[1];
    const float* ea   = (const float*)d_in[2];
    // d_in[3] = y (unused); d_in[4] = adj (algebraically eliminated — never read)
    const float* W1   = (const float*)d_in[5];
    const float* as1  = (const float*)d_in[6];
    const float* ad1  = (const float*)d_in[7];
    const float* We1  = (const float*)d_in[8];
    const float* Wp1  = (const float*)d_in[9];
    const float* asp1 = (const float*)d_in[10];
    const float* adp1 = (const float*)d_in[11];
    const float* Wep1 = (const float*)d_in[12];
    const float* Wp2  = (const float*)d_in[13];
    const float* asp2 = (const float*)d_in[14];
    const float* adp2 = (const float*)d_in[15];
    const float* Wep2 = (const float*)d_in[16];
    const float* Wf1  = (const float*)d_in[17];
    const float* bf1  = (const float*)d_in[18];
    const float* Wf2  = (const float*)d_in[19];
    const float* bf2  = (const float*)d_in[20];
    float* out = (float*)d_out;

    const int* srcA = ei;
    const int* dstA = ei + EE;

    char* wp = (char*)d_ws;
    auto carve = [&](size_t bytes)->char*{
        char* p = wp;
        wp += (bytes + 255) & ~(size_t)255;
        return p;
    };
    float* h1    = (float*)carve((size_t)NN*HID*4);
    float* hs1   = (float*)carve((size_t)NN*NHEADS*4);
    float* hd1   = (float*)carve((size_t)NN*NHEADS*4);
    float* ew1s  = (float*)carve((size_t)EE*NHEADS*4);
    float* ewp1s = (float*)carve((size_t)EE*4);
    float* x1    = (float*)carve((size_t)NN*HID*4);
    float* hp1   = (float*)carve((size_t)NN*C1*4);
    float* hsp   = (float*)carve((size_t)NN*4);
    float* hdp   = (float*)carve((size_t)NN*4);
    float* s1    = (float*)carve((size_t)NN*C1*4);
    float* ssoft = (float*)carve((size_t)NN*C1*4);
    float* T     = (float*)carve((size_t)NN*C1*4);
    // --- zero-init region (contiguous): x2, adj2, Gm ---
    float* x2    = (float*)carve((size_t)NB*C1*HID*4);   // 61440 B (256-aligned)
    float* adj2  = (float*)carve((size_t)NB*C1*C1*4);    // 65536 B
    float* Gm    = (float*)carve((size_t)NB*C1*C1*4);    // 65536 B
    // ---------------------------------------------------
    float* x3    = (float*)carve((size_t)NB*C2*HID*4);
    float* scal  = (float*)carve(16*4);
    int* histD   = (int*)carve((size_t)NB*CH*NPG*4);     // 1 MB
    int* histS   = (int*)carve((size_t)NB*CH*NPG*4);     // 1 MB
    int* deg     = (int*)carve((size_t)NN*4);
    int* degS    = (int*)carve((size_t)NN*4);
    int* rowptr  = (int*)carve((size_t)(NN+1)*4);
    int* rowptrS = (int*)carve((size_t)(NN+1)*4);
    int2* se     = (int2*)carve((size_t)EE*8);
    int* nbrS    = (int*)carve((size_t)EE*4);
    int* unbr    = (int*)carve((size_t)EE*4);
    int* ucnt    = (int*)carve((size_t)NN*4);

    hipMemsetAsync(scal, 0, 16*4, stream);
    hipMemsetAsync(x2, 0, (size_t)(NB*C1*HID + 2*NB*C1*C1)*4, stream);  // x2+adj2+Gm

    const int TB = 256;
    dim3 gN((NN + TB - 1)/TB);

    // merged: per-chunk dual LDS histograms (256 blocks) + node projection (64 blocks)
    k_hist_chunk<<<dim3(256 + 64), TB, 0, stream>>>(srcA, dstA, histD, histS,
                                                    x, W1, as1, ad1, h1, hs1, hd1);
    // per-(g,n) chunk scan (in place) + deg/degS
    k_cumhist<<<dim3(128), TB, 0, stream>>>(histD, histS, deg, degS);
    // node-level scans -> rowptr/rowptrS
    k_scan2f<<<dim3(2), 1024, 0, stream>>>(deg, degS, rowptr, rowptrS);
    // deterministic scatter (LDS atomics only)
    k_scatter_det<<<dim3(256), TB, 0, stream>>>(srcA, dstA, rowptr, rowptrS,
                                                histD, histS, se, nbrS);

    // merged: edge projections (2048 blocks) + dedup (64 blocks)
    k_proj_dedup<<<dim3(2048 + 64), TB, 0, stream>>>(ea, We1, Wep1, se, ew1s, ewp1s,
                                                     rowptrS, nbrS, unbr, ucnt, scal);

    // conv1: thread per (node, head, 3-ch half), batched-4 online softmax
    k_conv1_agg<<<dim3(NN*NHEADS*2/TB), TB, 0, stream>>>(se, rowptr, h1, hs1, hd1, ew1s, x1);

    // pool-conv1
    k_node_proj_p1<<<gN, TB, 0, stream>>>(x1, Wp1, asp1, adp1, hp1, hsp, hdp);
    k_pool1_agg<<<dim3(NN*8/TB), TB, 0, stream>>>(se, rowptr, hp1, hsp, hdp, ewp1s, s1);

    // diffpool1
    k_soft32<<<gN, TB, 0, stream>>>(s1, ssoft);
    k_T<<<dim3(NN*8/TB), TB, 0, stream>>>(rowptrS, unbr, ucnt, ssoft, T);
    k_partials<<<dim3(16, NB), TB, 0, stream>>>(ssoft, T, x1, adj2, Gm, x2);
    k_finalize<<<dim3(NB), TB, 0, stream>>>(adj2, Gm, scal);

    // fused tail: pool-conv2 + diffpool2 + reg2
    k_tail<<<dim3(NB), TB, 0, stream>>>(x2, adj2, Wp2, asp2, adp2, Wep2, x3, scal);

    // MLP + output
    k_mlp<<<1, 512, 0, stream>>>(x3, Wf1, bf1, Wf2, bf2, scal, out);
}